// Round 12
// baseline (591.183 us; speedup 1.0000x reference)
//
#include <hip/hip_runtime.h>
#include <hip/hip_fp16.h>
#include <math.h>

#define BSHIFT 7          // 128 dst-nodes per bucket (requires N < 65536 for 16-bit packing)
#define CHUNK  8192       // edges per bucketing block
#define CAP    6144       // padded edge capacity per bucket (mean 4224, +29 sigma)

__device__ inline __half2 habs2_(__half2 x){
  union { __half2 h; unsigned u; } c; c.h = x; c.u &= 0x7FFF7FFFu; return c.h;
}
// lrelu(x) = 0.6x + 0.4|x|  (slope 0.2)
__device__ inline __half2 lrelu2_(__half2 x, __half2 c06, __half2 c04){
  return __hfma2(c04, habs2_(x), __hmul2(c06, x));
}

// ---------------- fused: bucket scatter (blocks < bb) | gemm1 64->2x128 fp16 (blocks >= bb) ----------------
__global__ __launch_bounds__(256) void k_pre(const int* __restrict__ ei, int E, int N, int NB,
    int* __restrict__ bfill, unsigned* __restrict__ ebuf,
    const float* __restrict__ X,
    const float* __restrict__ Wl, const float* __restrict__ bl,
    const float* __restrict__ Wr, const float* __restrict__ br,
    __half* __restrict__ outl, __half* __restrict__ outr, int bb){
  __shared__ float xs[32][64];           // 8KB; bucket path aliases it as int hist[]
  if ((int)blockIdx.x < bb){
    int* hist = (int*)&xs[0][0];
    int base = blockIdx.x*CHUNK;
    int EL = E + N;
    int end = min(base + CHUNK, EL);
    for (int i = threadIdx.x; i < NB; i += 256) hist[i] = 0;
    __syncthreads();
    for (int e = base + threadIdx.x; e < end; e += 256){
      int d = (e < E) ? ei[E + e] : (e - E);
      atomicAdd(&hist[d >> BSHIFT], 1);
    }
    __syncthreads();
    for (int b = threadIdx.x; b < NB; b += 256){
      int c = hist[b];
      hist[b] = (c > 0) ? (b*CAP + atomicAdd(&bfill[b], c)) : 0;
    }
    __syncthreads();
    for (int e = base + threadIdx.x; e < end; e += 256){
      int s, d;
      if (e < E){ s = ei[e]; d = ei[E + e]; } else { s = d = e - E; }
      int pos = atomicAdd(&hist[d >> BSHIFT], 1);
      ebuf[pos] = (unsigned)s | ((unsigned)d << 16);
    }
  } else {
    const int tid = threadIdx.x;
    const int n0 = ((int)blockIdx.x - bb)*32;
    for (int t = tid; t < 32*64; t += 256){
      int r = t >> 6, c = t & 63;
      int node = n0 + r;
      xs[r][c] = (node < N) ? X[(size_t)node*64 + c] : 0.f;
    }
    __syncthreads();
    const int jg = tid & 63;
    const int ng = tid >> 6;
    const int q  = jg*4;
    const bool isL = (q < 128);
    const float* W = isL ? Wl : Wr;
    const int jj   = isL ? q : q - 128;
    const float* bbp = isL ? bl : br;
    __half* OUT    = isL ? outl : outr;
    const float4 bias4 = *(const float4*)(bbp + jj);
    float acc[8][4];
    #pragma unroll
    for (int n = 0; n < 8; ++n){ acc[n][0]=acc[n][1]=acc[n][2]=acc[n][3]=0.f; }
    for (int k = 0; k < 64; k += 4){
      const float4 w0 = *(const float4*)(W + (size_t)(k+0)*128 + jj);
      const float4 w1 = *(const float4*)(W + (size_t)(k+1)*128 + jj);
      const float4 w2 = *(const float4*)(W + (size_t)(k+2)*128 + jj);
      const float4 w3 = *(const float4*)(W + (size_t)(k+3)*128 + jj);
      #pragma unroll
      for (int n = 0; n < 8; ++n){
        const float4 xv = *(const float4*)(&xs[ng*8 + n][k]);
        acc[n][0] = fmaf(xv.w,w3.x, fmaf(xv.z,w2.x, fmaf(xv.y,w1.x, fmaf(xv.x,w0.x, acc[n][0]))));
        acc[n][1] = fmaf(xv.w,w3.y, fmaf(xv.z,w2.y, fmaf(xv.y,w1.y, fmaf(xv.x,w0.y, acc[n][1]))));
        acc[n][2] = fmaf(xv.w,w3.z, fmaf(xv.z,w2.z, fmaf(xv.y,w1.z, fmaf(xv.x,w0.z, acc[n][2]))));
        acc[n][3] = fmaf(xv.w,w3.w, fmaf(xv.z,w2.w, fmaf(xv.y,w1.w, fmaf(xv.x,w0.w, acc[n][3]))));
      }
    }
    #pragma unroll
    for (int n = 0; n < 8; ++n){
      int node = n0 + ng*8 + n;
      if (node < N){
        union { __half2 h[2]; uint2 u; } cv;
        cv.h[0] = __floats2half2_rn(acc[n][0]+bias4.x, acc[n][1]+bias4.y);
        cv.h[1] = __floats2half2_rn(acc[n][2]+bias4.z, acc[n][3]+bias4.w);
        *(uint2*)(OUT + (size_t)node*128 + jj) = cv.u;
      }
    }
  }
}

// per-bucket: per-node counts, LDS scan -> rstart/rend (+ degree histogram), place edges. 1024 thr.
__global__ __launch_bounds__(1024) void k_fine(const unsigned* __restrict__ ebuf,
    const int* __restrict__ bfill, int N, int NB,
    int* __restrict__ rstart, int* __restrict__ rend, int* __restrict__ esrc,
    int* __restrict__ dh){
  __shared__ int cnt[128];
  __shared__ int sc[128];
  __shared__ int base[128];
  int b = blockIdx.x;
  int n0 = b << BSHIFT;
  int nn = min(128, N - n0);
  int e0 = b*CAP;
  int e1 = e0 + bfill[b];
  if (threadIdx.x < 128) cnt[threadIdx.x] = 0;
  __syncthreads();
  for (int e = e0 + threadIdx.x; e < e1; e += 1024)
    atomicAdd(&cnt[(ebuf[e] >> 16) & 127], 1);
  __syncthreads();
  if (threadIdx.x < 128) sc[threadIdx.x] = cnt[threadIdx.x];
  __syncthreads();
  for (int off = 1; off < 128; off <<= 1){
    int v = 0;
    if (threadIdx.x < 128 && (int)threadIdx.x >= off) v = sc[threadIdx.x - off];
    __syncthreads();
    if (threadIdx.x < 128) sc[threadIdx.x] += v;
    __syncthreads();
  }
  if (threadIdx.x < 128){
    int bs = e0 + sc[threadIdx.x] - cnt[threadIdx.x];
    base[threadIdx.x] = bs;
    if ((int)threadIdx.x < nn){
      rstart[n0 + threadIdx.x] = bs;
      rend[n0 + threadIdx.x]   = bs + cnt[threadIdx.x];
      atomicAdd(&dh[511 - min(cnt[threadIdx.x], 511)], 1);   // degree histogram (descending bins)
    }
    cnt[threadIdx.x] = 0;
  }
  __syncthreads();
  for (int e = e0 + threadIdx.x; e < e1; e += 1024){
    unsigned pk = ebuf[e];
    int local = (int)(pk >> 16) & 127;
    int pos = base[local] + atomicAdd(&cnt[local], 1);
    esrc[pos] = (int)(pk & 0xffffu);
  }
}

__global__ __launch_bounds__(512) void k_dscan(const int* __restrict__ dh, int* __restrict__ dfill){
  __shared__ int s[512];
  int tid = threadIdx.x;
  int v = dh[tid];
  s[tid] = v; __syncthreads();
  for (int off = 1; off < 512; off <<= 1){
    int t = (tid >= off) ? s[tid - off] : 0;
    __syncthreads();
    s[tid] += t;
    __syncthreads();
  }
  dfill[tid] = s[tid] - v;
}

__global__ __launch_bounds__(256) void k_dperm(const int* __restrict__ rstart, const int* __restrict__ rend,
                                               int N, int* __restrict__ dfill, int* __restrict__ perm){
  __shared__ int h[512];
  __shared__ int mybin[1024];
  int base_n = blockIdx.x*1024;
  for (int i = threadIdx.x; i < 512; i += 256) h[i] = 0;
  __syncthreads();
  #pragma unroll
  for (int k = 0; k < 4; ++k){
    int n = base_n + k*256 + threadIdx.x;
    if (n < N){
      int deg = rend[n] - rstart[n];
      int b = 511 - min(deg, 511);
      mybin[k*256 + threadIdx.x] = b;
      atomicAdd(&h[b], 1);
    }
  }
  __syncthreads();
  for (int i = threadIdx.x; i < 512; i += 256){
    int c = h[i];
    h[i] = c ? atomicAdd(&dfill[i], c) : 0;
  }
  __syncthreads();
  #pragma unroll
  for (int k = 0; k < 4; ++k){
    int n = base_n + k*256 + threadIdx.x;
    if (n < N){
      int pos = atomicAdd(&h[mybin[k*256 + threadIdx.x]], 1);
      perm[pos] = n;
    }
  }
}

// ---------------- gemm2 (128 -> 2x64 fp16), BN-affine (from raw sums) on fp16 input ----------------
__global__ __launch_bounds__(256) void k_gemm2(const __half2* __restrict__ X2,
    const float* __restrict__ Wl, const float* __restrict__ bl,
    const float* __restrict__ Wr, const float* __restrict__ br,
    __half* __restrict__ outl, __half* __restrict__ outr, int N,
    const float* __restrict__ bsum, const float* __restrict__ bsq,
    const float* __restrict__ gam, const float* __restrict__ bet){
  __shared__ float xs[32][128];
  const int tid = threadIdx.x;
  const int n0 = blockIdx.x*32;
  const float invN = 1.f/(float)N;
  for (int t = tid; t < 32*64; t += 256){
    int r = t >> 6, c2 = t & 63, c = c2*2;
    int node = n0 + r;
    float2 v = (node < N) ? __half22float2(X2[(size_t)node*64 + c2]) : make_float2(0.f,0.f);
    float m0 = bsum[c]*invN,   m1 = bsum[c+1]*invN;
    float r0 = rsqrtf(bsq[c]*invN   - m0*m0 + 1e-5f);
    float r1 = rsqrtf(bsq[c+1]*invN - m1*m1 + 1e-5f);
    v.x = (v.x - m0) * r0 * gam[c  ] + bet[c  ];
    v.y = (v.y - m1) * r1 * gam[c+1] + bet[c+1];
    xs[r][c] = v.x; xs[r][c+1] = v.y;
  }
  __syncthreads();
  const int jg = tid & 31;
  const int ng = tid >> 5;
  const int q  = jg*4;
  const bool isL = (q < 64);
  const float* W = isL ? Wl : Wr;
  const int jj   = isL ? q : q - 64;
  const float* bbp = isL ? bl : br;
  __half* OUT    = isL ? outl : outr;
  const float4 bias4 = *(const float4*)(bbp + jj);
  float acc[4][4];
  #pragma unroll
  for (int n = 0; n < 4; ++n){ acc[n][0]=acc[n][1]=acc[n][2]=acc[n][3]=0.f; }
  for (int k = 0; k < 128; k += 4){
    const float4 w0 = *(const float4*)(W + (size_t)(k+0)*64 + jj);
    const float4 w1 = *(const float4*)(W + (size_t)(k+1)*64 + jj);
    const float4 w2 = *(const float4*)(W + (size_t)(k+2)*64 + jj);
    const float4 w3 = *(const float4*)(W + (size_t)(k+3)*64 + jj);
    #pragma unroll
    for (int n = 0; n < 4; ++n){
      const float4 xv = *(const float4*)(&xs[ng*4 + n][k]);
      acc[n][0] = fmaf(xv.w,w3.x, fmaf(xv.z,w2.x, fmaf(xv.y,w1.x, fmaf(xv.x,w0.x, acc[n][0]))));
      acc[n][1] = fmaf(xv.w,w3.y, fmaf(xv.z,w2.y, fmaf(xv.y,w1.y, fmaf(xv.x,w0.y, acc[n][1]))));
      acc[n][2] = fmaf(xv.w,w3.z, fmaf(xv.z,w2.z, fmaf(xv.y,w1.z, fmaf(xv.x,w0.z, acc[n][2]))));
      acc[n][3] = fmaf(xv.w,w3.w, fmaf(xv.z,w2.w, fmaf(xv.y,w1.w, fmaf(xv.x,w0.w, acc[n][3]))));
    }
  }
  #pragma unroll
  for (int n = 0; n < 4; ++n){
    int node = n0 + ng*4 + n;
    if (node < N){
      union { __half2 h[2]; uint2 u; } cv;
      cv.h[0] = __floats2half2_rn(acc[n][0]+bias4.x, acc[n][1]+bias4.y);
      cv.h[1] = __floats2half2_rn(acc[n][2]+bias4.z, acc[n][3]+bias4.w);
      *(uint2*)(OUT + (size_t)node*64 + jj) = cv.u;
    }
  }
}

// ---------------- GAT layer 1 + fused BN1 stats: 4 nodes/wave (degree-sorted), rotated batch-4 ----------------
__global__ __launch_bounds__(256, 6) void k_gat1(const __half* __restrict__ xl, const __half* __restrict__ xr,
    const int* __restrict__ rstart, const int* __restrict__ rend,
    const int* __restrict__ esrc, const int* __restrict__ perm,
    const float* __restrict__ att, const float* __restrict__ bias,
    __half* __restrict__ h1, int N,
    float* __restrict__ bn_sum, float* __restrict__ bn_sq){
  __shared__ float bs[128], bq[128];
  if (threadIdx.x < 128){ bs[threadIdx.x] = 0.f; bq[threadIdx.x] = 0.f; }
  __syncthreads();
  int wv = (blockIdx.x*256 + threadIdx.x) >> 6;
  int lane = threadIdx.x & 63;
  int g = lane >> 4;
  int t = lane & 15;
  int idx = wv*4 + g;
  bool live = idx < N;
  int nd = perm[min(idx, N-1)];
  int c0 = t*8;
  const __half2 c06 = __float2half2_rn(0.6f);
  const __half2 c04 = __float2half2_rn(0.4f);
  union { uint4 u; __half2 h[4]; } xru;
  xru.u = *(const uint4*)(xr + (size_t)nd*128 + c0);
  float4 a0 = *(const float4*)(att + c0);
  float4 a1 = *(const float4*)(att + c0 + 4);
  __half2 av2[4] = { __floats2half2_rn(a0.x,a0.y), __floats2half2_rn(a0.z,a0.w),
                     __floats2half2_rn(a1.x,a1.y), __floats2half2_rn(a1.z,a1.w) };
  int r0 = rstart[nd];
  int r1 = rend[nd];
  int d  = r1 - r0;
  d = max(d, __shfl_xor(d, 16));
  d = max(d, __shfl_xor(d, 32));
  const char* xb = (const char*)xl;
  const unsigned cb = (unsigned)(c0*2);
  float s = 0.f;
  __half2 acc2[4];
  #pragma unroll
  for (int k = 0; k < 4; ++k) acc2[k] = __float2half2_rn(0.f);
  union V { uint4 u; __half2 h[4]; } cur[4], nxt[4];
  #pragma unroll
  for (int q = 0; q < 4; ++q){
    unsigned j = (unsigned)esrc[r0 + q] & 0xFFFFu;   // unclamped (esrc has slack); validity masks w
    cur[q].u = *(const uint4*)(xb + ((j << 8) + cb));
  }
  for (int i = 0; i < d; i += 4){
    #pragma unroll
    for (int q = 0; q < 4; ++q){
      unsigned j = (unsigned)esrc[r0 + i + 4 + q] & 0xFFFFu;
      nxt[q].u = *(const uint4*)(xb + ((j << 8) + cb));
    }
    #pragma unroll
    for (int q = 0; q < 4; ++q){
      bool valid = (r0 + i + q) < r1;
      __half2 p2 = __float2half2_rn(0.f);
      #pragma unroll
      for (int k = 0; k < 4; ++k){
        __half2 m2 = __hadd2(cur[q].h[k], xru.h[k]);
        p2 = __hfma2(lrelu2_(m2, c06, c04), av2[k], p2);
      }
      float p = __low2float(p2) + __high2float(p2);
      p += __shfl_xor(p, 1);
      p += __shfl_xor(p, 2);
      float w = valid ? __expf(p) : 0.f;
      s += w;
      __half2 w2 = __float2half2_rn(w);
      #pragma unroll
      for (int k = 0; k < 4; ++k) acc2[k] = __hfma2(w2, cur[q].h[k], acc2[k]);
    }
    #pragma unroll
    for (int q = 0; q < 4; ++q) cur[q] = nxt[q];
  }
  if (live){
    float inv = 1.f/s;
    float4 b0 = *(const float4*)(bias + c0);
    float4 b1 = *(const float4*)(bias + c0 + 4);
    float bv[8] = {b0.x,b0.y,b0.z,b0.w,b1.x,b1.y,b1.z,b1.w};
    union { __half2 h[4]; uint4 u; } o;
    #pragma unroll
    for (int k = 0; k < 4; ++k){
      float f0 = fmaxf(__low2float(acc2[k])*inv  + bv[2*k],   0.f);
      float f1 = fmaxf(__high2float(acc2[k])*inv + bv[2*k+1], 0.f);
      o.h[k] = __floats2half2_rn(f0, f1);
      atomicAdd(&bs[c0 + 2*k],     f0);
      atomicAdd(&bs[c0 + 2*k + 1], f1);
      atomicAdd(&bq[c0 + 2*k],     f0*f0);
      atomicAdd(&bq[c0 + 2*k + 1], f1*f1);
    }
    *(uint4*)(h1 + (size_t)nd*128 + c0) = o.u;
  }
  __syncthreads();
  if (threadIdx.x < 128){
    atomicAdd(&bn_sum[threadIdx.x], bs[threadIdx.x]);
    atomicAdd(&bn_sq[threadIdx.x],  bq[threadIdx.x]);
  }
}

// ---------------- GAT layer 2 + fused BN2 stats: 8 nodes/wave (degree-sorted), rotated batch-4 ----------------
__global__ __launch_bounds__(256, 6) void k_gat2(const __half* __restrict__ xl, const __half* __restrict__ xr,
    const int* __restrict__ rstart, const int* __restrict__ rend,
    const int* __restrict__ esrc, const int* __restrict__ perm,
    const float* __restrict__ att, const float* __restrict__ bias,
    __half* __restrict__ h2, int N,
    float* __restrict__ bn_sum, float* __restrict__ bn_sq){
  __shared__ float bs[64], bq[64];
  if (threadIdx.x < 64){ bs[threadIdx.x] = 0.f; bq[threadIdx.x] = 0.f; }
  __syncthreads();
  int wv = (blockIdx.x*256 + threadIdx.x) >> 6;
  int lane = threadIdx.x & 63;
  int g = lane >> 3;
  int t = lane & 7;
  int idx = wv*8 + g;
  bool live = idx < N;
  int nd = perm[min(idx, N-1)];
  int c0 = t*8;
  const __half2 c06 = __float2half2_rn(0.6f);
  const __half2 c04 = __float2half2_rn(0.4f);
  union { uint4 u; __half2 h[4]; } xru;
  xru.u = *(const uint4*)(xr + (size_t)nd*64 + c0);
  float4 a0 = *(const float4*)(att + c0);
  float4 a1 = *(const float4*)(att + c0 + 4);
  __half2 av2[4] = { __floats2half2_rn(a0.x,a0.y), __floats2half2_rn(a0.z,a0.w),
                     __floats2half2_rn(a1.x,a1.y), __floats2half2_rn(a1.z,a1.w) };
  int r0 = rstart[nd];
  int r1 = rend[nd];
  int d  = r1 - r0;
  d = max(d, __shfl_xor(d, 8));
  d = max(d, __shfl_xor(d, 16));
  d = max(d, __shfl_xor(d, 32));
  const char* xb = (const char*)xl;
  const unsigned cb = (unsigned)(c0*2);
  float s = 0.f;
  __half2 acc2[4];
  #pragma unroll
  for (int k = 0; k < 4; ++k) acc2[k] = __float2half2_rn(0.f);
  union V { uint4 u; __half2 h[4]; } cur[4], nxt[4];
  #pragma unroll
  for (int q = 0; q < 4; ++q){
    unsigned j = (unsigned)esrc[r0 + q] & 0xFFFFu;
    cur[q].u = *(const uint4*)(xb + ((j << 7) + cb));
  }
  for (int i = 0; i < d; i += 4){
    #pragma unroll
    for (int q = 0; q < 4; ++q){
      unsigned j = (unsigned)esrc[r0 + i + 4 + q] & 0xFFFFu;
      nxt[q].u = *(const uint4*)(xb + ((j << 7) + cb));
    }
    #pragma unroll
    for (int q = 0; q < 4; ++q){
      bool valid = (r0 + i + q) < r1;
      __half2 p2 = __float2half2_rn(0.f);
      #pragma unroll
      for (int k = 0; k < 4; ++k){
        __half2 m2 = __hadd2(cur[q].h[k], xru.h[k]);
        p2 = __hfma2(lrelu2_(m2, c06, c04), av2[k], p2);
      }
      float p = __low2float(p2) + __high2float(p2);
      p += __shfl_xor(p, 1);
      p += __shfl_xor(p, 2);
      p += __shfl_xor(p, 4);
      float w = valid ? __expf(p) : 0.f;
      s += w;
      __half2 w2 = __float2half2_rn(w);
      #pragma unroll
      for (int k = 0; k < 4; ++k) acc2[k] = __hfma2(w2, cur[q].h[k], acc2[k]);
    }
    #pragma unroll
    for (int q = 0; q < 4; ++q) cur[q] = nxt[q];
  }
  if (live){
    float inv = 1.f/s;
    float4 b0 = *(const float4*)(bias + c0);
    float4 b1 = *(const float4*)(bias + c0 + 4);
    float bv[8] = {b0.x,b0.y,b0.z,b0.w,b1.x,b1.y,b1.z,b1.w};
    union { __half2 h[4]; uint4 u; } o;
    #pragma unroll
    for (int k = 0; k < 4; ++k){
      float f0 = fmaxf(__low2float(acc2[k])*inv  + bv[2*k],   0.f);
      float f1 = fmaxf(__high2float(acc2[k])*inv + bv[2*k+1], 0.f);
      o.h[k] = __floats2half2_rn(f0, f1);
      atomicAdd(&bs[c0 + 2*k],     f0);
      atomicAdd(&bs[c0 + 2*k + 1], f1);
      atomicAdd(&bq[c0 + 2*k],     f0*f0);
      atomicAdd(&bq[c0 + 2*k + 1], f1*f1);
    }
    *(uint4*)(h2 + (size_t)nd*64 + c0) = o.u;
  }
  __syncthreads();
  if (threadIdx.x < 64){
    atomicAdd(&bn_sum[threadIdx.x], bs[threadIdx.x]);
    atomicAdd(&bn_sq[threadIdx.x],  bq[threadIdx.x]);
  }
}

// ---------------- pooling + head fused: BN2 final inline, writes d_out directly ----------------
__global__ __launch_bounds__(256) void k_pool(const __half* __restrict__ h2, const int* __restrict__ batch, int N,
    const float* __restrict__ bsum, const float* __restrict__ bsq,
    const float* __restrict__ g, const float* __restrict__ b,
    const float* __restrict__ lw, const float* __restrict__ lb,
    float* __restrict__ out){
  int gr = blockIdx.x;
  int lo = 0, hi = N;
  while (lo < hi){ int mid = (lo+hi)>>1; if (batch[mid] < gr) lo = mid+1; else hi = mid; }
  int r0 = lo;
  lo = r0; hi = N;
  while (lo < hi){ int mid = (lo+hi)>>1; if (batch[mid] < gr+1) lo = mid+1; else hi = mid; }
  int r1 = lo;
  int c = threadIdx.x & 63;
  int sub = threadIdx.x >> 6;
  const float invN = 1.f/(float)N;
  float m = bsum[c]*invN;
  float rs = rsqrtf(bsq[c]*invN - m*m + 1e-5f);
  float aff_s = rs*g[c];
  float aff_b = b[c] - m*aff_s;
  float s = 0.f, mx = -INFINITY;
  for (int r = r0 + sub; r < r1; r += 4){
    float v = __half2float(h2[(size_t)r*64 + c])*aff_s + aff_b;
    s += v; mx = fmaxf(mx, v);
  }
  __shared__ float ls[256], lm[256], ft[192];
  ls[threadIdx.x] = s; lm[threadIdx.x] = mx;
  __syncthreads();
  if (threadIdx.x < 64){
    float S = ls[c] + ls[64+c] + ls[128+c] + ls[192+c];
    float M = fmaxf(fmaxf(lm[c], lm[64+c]), fmaxf(lm[128+c], lm[192+c]));
    float cnt = (float)max(r1 - r0, 1);
    ft[c]       = S;
    ft[64 + c]  = S/cnt;
    ft[128 + c] = M;
  }
  __syncthreads();
  if (threadIdx.x < 2){
    float acc = lb[threadIdx.x];
    #pragma unroll 4
    for (int k = 0; k < 192; ++k) acc += ft[k] * lw[k*2 + threadIdx.x];
    out[gr*2 + threadIdx.x] = acc;
  }
}

extern "C" void kernel_launch(void* const* d_in, const int* in_sizes, int n_in,
                              void* d_out, int out_size, void* d_ws, size_t ws_size,
                              hipStream_t stream) {
  const float* x    = (const float*)d_in[0];
  const int*   ei   = (const int*)d_in[1];
  const int*   batch= (const int*)d_in[2];
  const float* W1l  = (const float*)d_in[3];
  const float* b1l  = (const float*)d_in[4];
  const float* W1r  = (const float*)d_in[5];
  const float* b1r  = (const float*)d_in[6];
  const float* att1 = (const float*)d_in[7];
  const float* bias1= (const float*)d_in[8];
  const float* W2l  = (const float*)d_in[9];
  const float* b2l  = (const float*)d_in[10];
  const float* W2r  = (const float*)d_in[11];
  const float* b2r  = (const float*)d_in[12];
  const float* att2 = (const float*)d_in[13];
  const float* bias2= (const float*)d_in[14];
  const float* g1   = (const float*)d_in[15];
  const float* be1  = (const float*)d_in[16];
  const float* g2   = (const float*)d_in[17];
  const float* be2  = (const float*)d_in[18];
  const float* lw   = (const float*)d_in[19];
  const float* lb   = (const float*)d_in[20];

  const int N  = in_sizes[0] / 64;
  const int E  = in_sizes[1] / 2;
  const int EL = E + N;
  const int G  = 128;
  const int NB = (N + 127) >> BSHIFT;

  char* p = (char*)d_ws;
  auto carve = [&](size_t bytes)->char*{ char* r = p; p += (bytes + 255) & ~(size_t)255; return r; };
  // zero block: bfill(NB) + dh(512) + bn sums(384)
  int* zero   = (int*)carve((size_t)(NB + 512 + 384)*4);
  int* bfill  = zero;
  int* dh     = zero + NB;
  float* stats = (float*)(zero + NB + 512);
  float* bn1_sum = stats;
  float* bn1_sq  = stats + 128;
  float* bn2_sum = stats + 256;
  float* bn2_sq  = stats + 320;
  int* dfill  = (int*)carve((size_t)512*4);
  int* rstart = (int*)carve((size_t)N*4);
  int* rend   = (int*)carve((size_t)N*4);
  int* perm   = (int*)carve((size_t)N*4);
  unsigned* ebuf = (unsigned*)carve((size_t)NB*CAP*4);
  int* esrc   = (int*)carve((size_t)(NB*CAP + 1024)*4);   // +slack for unclamped pipeline reads
  __half* xl1 = (__half*)carve((size_t)N*128*2);
  __half* xr1 = (__half*)carve((size_t)N*128*2);
  __half* h1  = (__half*)carve((size_t)N*128*2);
  __half* xl2 = xl1;                    // xl1 block dead after k_gat1; holds xl2 | xr2
  __half* xr2 = xl1 + (size_t)N*64;
  __half* h2  = xr1;                    // xr1 block dead after k_gat1

  hipMemsetAsync(zero, 0, (size_t)(NB + 512 + 384)*4, stream);

  const int bb = (EL + CHUNK - 1)/CHUNK;
  const int gb = (N + 31)/32;
  const int db = (N + 1023)/1024;
  // fused: bucket (bb blocks) | gemm1 (gb blocks) — independent work, one dispatch
  k_pre<<<bb + gb, 256, 0, stream>>>(ei, E, N, NB, bfill, ebuf,
                                     x, W1l, b1l, W1r, b1r, xl1, xr1, bb);
  k_fine<<<NB, 1024, 0, stream>>>(ebuf, bfill, N, NB, rstart, rend, esrc, dh);
  k_dscan<<<1, 512, 0, stream>>>(dh, dfill);
  k_dperm<<<db, 256, 0, stream>>>(rstart, rend, N, dfill, perm);

  const int nb1 = ((N + 3)/4*64 + 255)/256;   // 4 nodes per wave
  const int nb2 = ((N + 7)/8*64 + 255)/256;   // 8 nodes per wave
  k_gat1<<<nb1, 256, 0, stream>>>(xl1, xr1, rstart, rend, esrc, perm, att1, bias1, h1, N,
                                  bn1_sum, bn1_sq);
  k_gemm2<<<gb, 256, 0, stream>>>((const __half2*)h1, W2l, b2l, W2r, b2r, xl2, xr2, N,
                                  bn1_sum, bn1_sq, g1, be1);
  k_gat2<<<nb2, 256, 0, stream>>>(xl2, xr2, rstart, rend, esrc, perm, att2, bias2, h2, N,
                                  bn2_sum, bn2_sq);
  k_pool<<<G, 256, 0, stream>>>(h2, batch, N, bn2_sum, bn2_sq, g2, be2, lw, lb, (float*)d_out);
}

// Round 13
// 483.902 us; speedup vs baseline: 1.2217x; 1.2217x over previous
//
#include <hip/hip_runtime.h>
#include <hip/hip_fp16.h>
#include <math.h>

#define BSHIFT 7          // 128 dst-nodes per bucket (requires N < 65536 for 16-bit packing)
#define CHUNK  8192       // edges per bucketing block
#define CAP    6144       // padded edge capacity per bucket (mean 4224, +29 sigma)

__device__ inline __half2 habs2_(__half2 x){
  union { __half2 h; unsigned u; } c; c.h = x; c.u &= 0x7FFF7FFFu; return c.h;
}
// lrelu(x) = 0.6x + 0.4|x|  (slope 0.2)
__device__ inline __half2 lrelu2_(__half2 x, __half2 c06, __half2 c04){
  return __hfma2(c04, habs2_(x), __hmul2(c06, x));
}

// ---------------- fused: bucket scatter (blocks < bb) | gemm1 64->2x128 fp16 (blocks >= bb) ----------------
__global__ __launch_bounds__(256) void k_pre(const int* __restrict__ ei, int E, int N, int NB,
    int* __restrict__ bfill, unsigned* __restrict__ ebuf,
    const float* __restrict__ X,
    const float* __restrict__ Wl, const float* __restrict__ bl,
    const float* __restrict__ Wr, const float* __restrict__ br,
    __half* __restrict__ outl, __half* __restrict__ outr, int bb){
  __shared__ float xs[32][64];           // 8KB; bucket path aliases it as int hist[]
  if ((int)blockIdx.x < bb){
    int* hist = (int*)&xs[0][0];
    int base = blockIdx.x*CHUNK;
    int EL = E + N;
    int end = min(base + CHUNK, EL);
    for (int i = threadIdx.x; i < NB; i += 256) hist[i] = 0;
    __syncthreads();
    for (int e = base + threadIdx.x; e < end; e += 256){
      int d = (e < E) ? ei[E + e] : (e - E);
      atomicAdd(&hist[d >> BSHIFT], 1);
    }
    __syncthreads();
    for (int b = threadIdx.x; b < NB; b += 256){
      int c = hist[b];
      hist[b] = (c > 0) ? (b*CAP + atomicAdd(&bfill[b], c)) : 0;
    }
    __syncthreads();
    for (int e = base + threadIdx.x; e < end; e += 256){
      int s, d;
      if (e < E){ s = ei[e]; d = ei[E + e]; } else { s = d = e - E; }
      int pos = atomicAdd(&hist[d >> BSHIFT], 1);
      ebuf[pos] = (unsigned)s | ((unsigned)d << 16);
    }
  } else {
    const int tid = threadIdx.x;
    const int n0 = ((int)blockIdx.x - bb)*32;
    for (int t = tid; t < 32*64; t += 256){
      int r = t >> 6, c = t & 63;
      int node = n0 + r;
      xs[r][c] = (node < N) ? X[(size_t)node*64 + c] : 0.f;
    }
    __syncthreads();
    const int jg = tid & 63;
    const int ng = tid >> 6;
    const int q  = jg*4;
    const bool isL = (q < 128);
    const float* W = isL ? Wl : Wr;
    const int jj   = isL ? q : q - 128;
    const float* bbp = isL ? bl : br;
    __half* OUT    = isL ? outl : outr;
    const float4 bias4 = *(const float4*)(bbp + jj);
    float acc[8][4];
    #pragma unroll
    for (int n = 0; n < 8; ++n){ acc[n][0]=acc[n][1]=acc[n][2]=acc[n][3]=0.f; }
    for (int k = 0; k < 64; k += 4){
      const float4 w0 = *(const float4*)(W + (size_t)(k+0)*128 + jj);
      const float4 w1 = *(const float4*)(W + (size_t)(k+1)*128 + jj);
      const float4 w2 = *(const float4*)(W + (size_t)(k+2)*128 + jj);
      const float4 w3 = *(const float4*)(W + (size_t)(k+3)*128 + jj);
      #pragma unroll
      for (int n = 0; n < 8; ++n){
        const float4 xv = *(const float4*)(&xs[ng*8 + n][k]);
        acc[n][0] = fmaf(xv.w,w3.x, fmaf(xv.z,w2.x, fmaf(xv.y,w1.x, fmaf(xv.x,w0.x, acc[n][0]))));
        acc[n][1] = fmaf(xv.w,w3.y, fmaf(xv.z,w2.y, fmaf(xv.y,w1.y, fmaf(xv.x,w0.y, acc[n][1]))));
        acc[n][2] = fmaf(xv.w,w3.z, fmaf(xv.z,w2.z, fmaf(xv.y,w1.z, fmaf(xv.x,w0.z, acc[n][2]))));
        acc[n][3] = fmaf(xv.w,w3.w, fmaf(xv.z,w2.w, fmaf(xv.y,w1.w, fmaf(xv.x,w0.w, acc[n][3]))));
      }
    }
    #pragma unroll
    for (int n = 0; n < 8; ++n){
      int node = n0 + ng*8 + n;
      if (node < N){
        union { __half2 h[2]; uint2 u; } cv;
        cv.h[0] = __floats2half2_rn(acc[n][0]+bias4.x, acc[n][1]+bias4.y);
        cv.h[1] = __floats2half2_rn(acc[n][2]+bias4.z, acc[n][3]+bias4.w);
        *(uint2*)(OUT + (size_t)node*128 + jj) = cv.u;
      }
    }
  }
}

// per-bucket: per-node counts, LDS scan -> rstart/rend (+ degree histogram), place edges. 1024 thr.
__global__ __launch_bounds__(1024) void k_fine(const unsigned* __restrict__ ebuf,
    const int* __restrict__ bfill, int N, int NB,
    int* __restrict__ rstart, int* __restrict__ rend, int* __restrict__ esrc,
    int* __restrict__ dh){
  __shared__ int cnt[128];
  __shared__ int sc[128];
  __shared__ int base[128];
  int b = blockIdx.x;
  int n0 = b << BSHIFT;
  int nn = min(128, N - n0);
  int e0 = b*CAP;
  int e1 = e0 + bfill[b];
  if (threadIdx.x < 128) cnt[threadIdx.x] = 0;
  __syncthreads();
  for (int e = e0 + threadIdx.x; e < e1; e += 1024)
    atomicAdd(&cnt[(ebuf[e] >> 16) & 127], 1);
  __syncthreads();
  if (threadIdx.x < 128) sc[threadIdx.x] = cnt[threadIdx.x];
  __syncthreads();
  for (int off = 1; off < 128; off <<= 1){
    int v = 0;
    if (threadIdx.x < 128 && (int)threadIdx.x >= off) v = sc[threadIdx.x - off];
    __syncthreads();
    if (threadIdx.x < 128) sc[threadIdx.x] += v;
    __syncthreads();
  }
  if (threadIdx.x < 128){
    int bs = e0 + sc[threadIdx.x] - cnt[threadIdx.x];
    base[threadIdx.x] = bs;
    if ((int)threadIdx.x < nn){
      rstart[n0 + threadIdx.x] = bs;
      rend[n0 + threadIdx.x]   = bs + cnt[threadIdx.x];
      atomicAdd(&dh[511 - min(cnt[threadIdx.x], 511)], 1);   // degree histogram (descending bins)
    }
    cnt[threadIdx.x] = 0;
  }
  __syncthreads();
  for (int e = e0 + threadIdx.x; e < e1; e += 1024){
    unsigned pk = ebuf[e];
    int local = (int)(pk >> 16) & 127;
    int pos = base[local] + atomicAdd(&cnt[local], 1);
    esrc[pos] = (int)(pk & 0xffffu);
  }
}

__global__ __launch_bounds__(512) void k_dscan(const int* __restrict__ dh, int* __restrict__ dfill){
  __shared__ int s[512];
  int tid = threadIdx.x;
  int v = dh[tid];
  s[tid] = v; __syncthreads();
  for (int off = 1; off < 512; off <<= 1){
    int t = (tid >= off) ? s[tid - off] : 0;
    __syncthreads();
    s[tid] += t;
    __syncthreads();
  }
  dfill[tid] = s[tid] - v;
}

__global__ __launch_bounds__(256) void k_dperm(const int* __restrict__ rstart, const int* __restrict__ rend,
                                               int N, int* __restrict__ dfill, int* __restrict__ perm){
  __shared__ int h[512];
  __shared__ int mybin[1024];
  int base_n = blockIdx.x*1024;
  for (int i = threadIdx.x; i < 512; i += 256) h[i] = 0;
  __syncthreads();
  #pragma unroll
  for (int k = 0; k < 4; ++k){
    int n = base_n + k*256 + threadIdx.x;
    if (n < N){
      int deg = rend[n] - rstart[n];
      int b = 511 - min(deg, 511);
      mybin[k*256 + threadIdx.x] = b;
      atomicAdd(&h[b], 1);
    }
  }
  __syncthreads();
  for (int i = threadIdx.x; i < 512; i += 256){
    int c = h[i];
    h[i] = c ? atomicAdd(&dfill[i], c) : 0;
  }
  __syncthreads();
  #pragma unroll
  for (int k = 0; k < 4; ++k){
    int n = base_n + k*256 + threadIdx.x;
    if (n < N){
      int pos = atomicAdd(&h[mybin[k*256 + threadIdx.x]], 1);
      perm[pos] = n;
    }
  }
}

// ---------------- gemm2 (128 -> 2x64 fp16), BN-affine (from raw sums) on fp16 input ----------------
__global__ __launch_bounds__(256) void k_gemm2(const __half2* __restrict__ X2,
    const float* __restrict__ Wl, const float* __restrict__ bl,
    const float* __restrict__ Wr, const float* __restrict__ br,
    __half* __restrict__ outl, __half* __restrict__ outr, int N,
    const float* __restrict__ bsum, const float* __restrict__ bsq,
    const float* __restrict__ gam, const float* __restrict__ bet){
  __shared__ float xs[32][128];
  const int tid = threadIdx.x;
  const int n0 = blockIdx.x*32;
  const float invN = 1.f/(float)N;
  for (int t = tid; t < 32*64; t += 256){
    int r = t >> 6, c2 = t & 63, c = c2*2;
    int node = n0 + r;
    float2 v = (node < N) ? __half22float2(X2[(size_t)node*64 + c2]) : make_float2(0.f,0.f);
    float m0 = bsum[c]*invN,   m1 = bsum[c+1]*invN;
    float r0 = rsqrtf(bsq[c]*invN   - m0*m0 + 1e-5f);
    float r1 = rsqrtf(bsq[c+1]*invN - m1*m1 + 1e-5f);
    v.x = (v.x - m0) * r0 * gam[c  ] + bet[c  ];
    v.y = (v.y - m1) * r1 * gam[c+1] + bet[c+1];
    xs[r][c] = v.x; xs[r][c+1] = v.y;
  }
  __syncthreads();
  const int jg = tid & 31;
  const int ng = tid >> 5;
  const int q  = jg*4;
  const bool isL = (q < 64);
  const float* W = isL ? Wl : Wr;
  const int jj   = isL ? q : q - 64;
  const float* bbp = isL ? bl : br;
  __half* OUT    = isL ? outl : outr;
  const float4 bias4 = *(const float4*)(bbp + jj);
  float acc[4][4];
  #pragma unroll
  for (int n = 0; n < 4; ++n){ acc[n][0]=acc[n][1]=acc[n][2]=acc[n][3]=0.f; }
  for (int k = 0; k < 128; k += 4){
    const float4 w0 = *(const float4*)(W + (size_t)(k+0)*64 + jj);
    const float4 w1 = *(const float4*)(W + (size_t)(k+1)*64 + jj);
    const float4 w2 = *(const float4*)(W + (size_t)(k+2)*64 + jj);
    const float4 w3 = *(const float4*)(W + (size_t)(k+3)*64 + jj);
    #pragma unroll
    for (int n = 0; n < 4; ++n){
      const float4 xv = *(const float4*)(&xs[ng*4 + n][k]);
      acc[n][0] = fmaf(xv.w,w3.x, fmaf(xv.z,w2.x, fmaf(xv.y,w1.x, fmaf(xv.x,w0.x, acc[n][0]))));
      acc[n][1] = fmaf(xv.w,w3.y, fmaf(xv.z,w2.y, fmaf(xv.y,w1.y, fmaf(xv.x,w0.y, acc[n][1]))));
      acc[n][2] = fmaf(xv.w,w3.z, fmaf(xv.z,w2.z, fmaf(xv.y,w1.z, fmaf(xv.x,w0.z, acc[n][2]))));
      acc[n][3] = fmaf(xv.w,w3.w, fmaf(xv.z,w2.w, fmaf(xv.y,w1.w, fmaf(xv.x,w0.w, acc[n][3]))));
    }
  }
  #pragma unroll
  for (int n = 0; n < 4; ++n){
    int node = n0 + ng*4 + n;
    if (node < N){
      union { __half2 h[2]; uint2 u; } cv;
      cv.h[0] = __floats2half2_rn(acc[n][0]+bias4.x, acc[n][1]+bias4.y);
      cv.h[1] = __floats2half2_rn(acc[n][2]+bias4.z, acc[n][3]+bias4.w);
      *(uint2*)(OUT + (size_t)node*64 + jj) = cv.u;
    }
  }
}

// ---------------- GAT layer 1: 4 nodes/wave (degree-sorted), rotated batch-4 gather pipeline ----------------
__global__ __launch_bounds__(256, 6) void k_gat1(const __half* __restrict__ xl, const __half* __restrict__ xr,
    const int* __restrict__ rstart, const int* __restrict__ rend,
    const int* __restrict__ esrc, const int* __restrict__ perm,
    const float* __restrict__ att, const float* __restrict__ bias,
    __half* __restrict__ h1, int N){
  int wv = (blockIdx.x*256 + threadIdx.x) >> 6;
  int lane = threadIdx.x & 63;
  int g = lane >> 4;
  int t = lane & 15;
  int idx = wv*4 + g;
  bool live = idx < N;
  int nd = perm[min(idx, N-1)];
  int c0 = t*8;
  const __half2 c06 = __float2half2_rn(0.6f);
  const __half2 c04 = __float2half2_rn(0.4f);
  union { uint4 u; __half2 h[4]; } xru;
  xru.u = *(const uint4*)(xr + (size_t)nd*128 + c0);
  float4 a0 = *(const float4*)(att + c0);
  float4 a1 = *(const float4*)(att + c0 + 4);
  __half2 av2[4] = { __floats2half2_rn(a0.x,a0.y), __floats2half2_rn(a0.z,a0.w),
                     __floats2half2_rn(a1.x,a1.y), __floats2half2_rn(a1.z,a1.w) };
  int r0 = rstart[nd];
  int r1 = rend[nd];
  int d  = r1 - r0;
  d = max(d, __shfl_xor(d, 16));
  d = max(d, __shfl_xor(d, 32));
  const char* xb = (const char*)xl;
  const unsigned cb = (unsigned)(c0*2);
  float s = 0.f;
  __half2 acc2[4];
  #pragma unroll
  for (int k = 0; k < 4; ++k) acc2[k] = __float2half2_rn(0.f);
  union V { uint4 u; __half2 h[4]; } cur[4], nxt[4];
  #pragma unroll
  for (int q = 0; q < 4; ++q){
    unsigned j = (unsigned)esrc[r0 + q] & 0xFFFFu;   // unclamped read (esrc has slack); validity masks w
    cur[q].u = *(const uint4*)(xb + ((j << 8) + cb));
  }
  for (int i = 0; i < d; i += 4){
    #pragma unroll
    for (int q = 0; q < 4; ++q){
      unsigned j = (unsigned)esrc[r0 + i + 4 + q] & 0xFFFFu;
      nxt[q].u = *(const uint4*)(xb + ((j << 8) + cb));
    }
    #pragma unroll
    for (int q = 0; q < 4; ++q){
      bool valid = (r0 + i + q) < r1;
      __half2 p2 = __float2half2_rn(0.f);
      #pragma unroll
      for (int k = 0; k < 4; ++k){
        __half2 m2 = __hadd2(cur[q].h[k], xru.h[k]);
        p2 = __hfma2(lrelu2_(m2, c06, c04), av2[k], p2);
      }
      float p = __low2float(p2) + __high2float(p2);
      p += __shfl_xor(p, 1);
      p += __shfl_xor(p, 2);
      float w = valid ? __expf(p) : 0.f;
      s += w;
      __half2 w2 = __float2half2_rn(w);
      #pragma unroll
      for (int k = 0; k < 4; ++k) acc2[k] = __hfma2(w2, cur[q].h[k], acc2[k]);
    }
    #pragma unroll
    for (int q = 0; q < 4; ++q) cur[q] = nxt[q];
  }
  if (live){
    float inv = 1.f/s;
    float4 b0 = *(const float4*)(bias + c0);
    float4 b1 = *(const float4*)(bias + c0 + 4);
    float bv[8] = {b0.x,b0.y,b0.z,b0.w,b1.x,b1.y,b1.z,b1.w};
    union { __half2 h[4]; uint4 u; } o;
    #pragma unroll
    for (int k = 0; k < 4; ++k){
      float2 af = __half22float2(acc2[k]);
      float f0 = fmaxf(af.x*inv + bv[2*k],   0.f);
      float f1 = fmaxf(af.y*inv + bv[2*k+1], 0.f);
      o.h[k] = __floats2half2_rn(f0, f1);
    }
    *(uint4*)(h1 + (size_t)nd*128 + c0) = o.u;
  }
}

// ---------------- GAT layer 2: 8 nodes/wave (degree-sorted), rotated batch-4 gather pipeline ----------------
__global__ __launch_bounds__(256, 6) void k_gat2(const __half* __restrict__ xl, const __half* __restrict__ xr,
    const int* __restrict__ rstart, const int* __restrict__ rend,
    const int* __restrict__ esrc, const int* __restrict__ perm,
    const float* __restrict__ att, const float* __restrict__ bias,
    __half* __restrict__ h2, int N){
  int wv = (blockIdx.x*256 + threadIdx.x) >> 6;
  int lane = threadIdx.x & 63;
  int g = lane >> 3;
  int t = lane & 7;
  int idx = wv*8 + g;
  bool live = idx < N;
  int nd = perm[min(idx, N-1)];
  int c0 = t*8;
  const __half2 c06 = __float2half2_rn(0.6f);
  const __half2 c04 = __float2half2_rn(0.4f);
  union { uint4 u; __half2 h[4]; } xru;
  xru.u = *(const uint4*)(xr + (size_t)nd*64 + c0);
  float4 a0 = *(const float4*)(att + c0);
  float4 a1 = *(const float4*)(att + c0 + 4);
  __half2 av2[4] = { __floats2half2_rn(a0.x,a0.y), __floats2half2_rn(a0.z,a0.w),
                     __floats2half2_rn(a1.x,a1.y), __floats2half2_rn(a1.z,a1.w) };
  int r0 = rstart[nd];
  int r1 = rend[nd];
  int d  = r1 - r0;
  d = max(d, __shfl_xor(d, 8));
  d = max(d, __shfl_xor(d, 16));
  d = max(d, __shfl_xor(d, 32));
  const char* xb = (const char*)xl;
  const unsigned cb = (unsigned)(c0*2);
  float s = 0.f;
  __half2 acc2[4];
  #pragma unroll
  for (int k = 0; k < 4; ++k) acc2[k] = __float2half2_rn(0.f);
  union V { uint4 u; __half2 h[4]; } cur[4], nxt[4];
  #pragma unroll
  for (int q = 0; q < 4; ++q){
    unsigned j = (unsigned)esrc[r0 + q] & 0xFFFFu;
    cur[q].u = *(const uint4*)(xb + ((j << 7) + cb));
  }
  for (int i = 0; i < d; i += 4){
    #pragma unroll
    for (int q = 0; q < 4; ++q){
      unsigned j = (unsigned)esrc[r0 + i + 4 + q] & 0xFFFFu;
      nxt[q].u = *(const uint4*)(xb + ((j << 7) + cb));
    }
    #pragma unroll
    for (int q = 0; q < 4; ++q){
      bool valid = (r0 + i + q) < r1;
      __half2 p2 = __float2half2_rn(0.f);
      #pragma unroll
      for (int k = 0; k < 4; ++k){
        __half2 m2 = __hadd2(cur[q].h[k], xru.h[k]);
        p2 = __hfma2(lrelu2_(m2, c06, c04), av2[k], p2);
      }
      float p = __low2float(p2) + __high2float(p2);
      p += __shfl_xor(p, 1);
      p += __shfl_xor(p, 2);
      p += __shfl_xor(p, 4);
      float w = valid ? __expf(p) : 0.f;
      s += w;
      __half2 w2 = __float2half2_rn(w);
      #pragma unroll
      for (int k = 0; k < 4; ++k) acc2[k] = __hfma2(w2, cur[q].h[k], acc2[k]);
    }
    #pragma unroll
    for (int q = 0; q < 4; ++q) cur[q] = nxt[q];
  }
  if (live){
    float inv = 1.f/s;
    float4 b0 = *(const float4*)(bias + c0);
    float4 b1 = *(const float4*)(bias + c0 + 4);
    float bv[8] = {b0.x,b0.y,b0.z,b0.w,b1.x,b1.y,b1.z,b1.w};
    union { __half2 h[4]; uint4 u; } o;
    #pragma unroll
    for (int k = 0; k < 4; ++k){
      float2 af = __half22float2(acc2[k]);
      float f0 = fmaxf(af.x*inv + bv[2*k],   0.f);
      float f1 = fmaxf(af.y*inv + bv[2*k+1], 0.f);
      o.h[k] = __floats2half2_rn(f0, f1);
    }
    *(uint4*)(h2 + (size_t)nd*64 + c0) = o.u;
  }
}

// ---------------- BN stats over fp16 activations ----------------
template<int C>
__global__ __launch_bounds__(256) void k_bnstats(const __half* __restrict__ h, int N,
    float* __restrict__ sum, float* __restrict__ sq){
  constexpr int RPB = 256/C;
  int c = threadIdx.x % C;
  int sub = threadIdx.x / C;
  float s = 0.f, q = 0.f;
  for (int r = blockIdx.x*RPB + sub; r < N; r += gridDim.x*RPB){
    float v = __half2float(h[(size_t)r*C + c]);
    s += v; q += v*v;
  }
  __shared__ float ls[256], lq[256];
  ls[threadIdx.x] = s; lq[threadIdx.x] = q;
  __syncthreads();
  if (threadIdx.x < C){
    float S = ls[c], Q = lq[c];
    #pragma unroll
    for (int u = 1; u < RPB; ++u){ S += ls[u*C + c]; Q += lq[u*C + c]; }
    atomicAdd(&sum[c], S);
    atomicAdd(&sq[c], Q);
  }
}

// ---------------- pooling + head fused: BN2 final inline, writes d_out directly ----------------
__global__ __launch_bounds__(256) void k_pool(const __half* __restrict__ h2, const int* __restrict__ batch, int N,
    const float* __restrict__ bsum, const float* __restrict__ bsq,
    const float* __restrict__ g, const float* __restrict__ b,
    const float* __restrict__ lw, const float* __restrict__ lb,
    float* __restrict__ out){
  int gr = blockIdx.x;
  int lo = 0, hi = N;
  while (lo < hi){ int mid = (lo+hi)>>1; if (batch[mid] < gr) lo = mid+1; else hi = mid; }
  int r0 = lo;
  lo = r0; hi = N;
  while (lo < hi){ int mid = (lo+hi)>>1; if (batch[mid] < gr+1) lo = mid+1; else hi = mid; }
  int r1 = lo;
  int c = threadIdx.x & 63;
  int sub = threadIdx.x >> 6;
  const float invN = 1.f/(float)N;
  float m = bsum[c]*invN;
  float rs = rsqrtf(bsq[c]*invN - m*m + 1e-5f);
  float aff_s = rs*g[c];
  float aff_b = b[c] - m*aff_s;
  float s = 0.f, mx = -INFINITY;
  for (int r = r0 + sub; r < r1; r += 4){
    float v = __half2float(h2[(size_t)r*64 + c])*aff_s + aff_b;
    s += v; mx = fmaxf(mx, v);
  }
  __shared__ float ls[256], lm[256], ft[192];
  ls[threadIdx.x] = s; lm[threadIdx.x] = mx;
  __syncthreads();
  if (threadIdx.x < 64){
    float S = ls[c] + ls[64+c] + ls[128+c] + ls[192+c];
    float M = fmaxf(fmaxf(lm[c], lm[64+c]), fmaxf(lm[128+c], lm[192+c]));
    float cnt = (float)max(r1 - r0, 1);
    ft[c]       = S;
    ft[64 + c]  = S/cnt;
    ft[128 + c] = M;
  }
  __syncthreads();
  if (threadIdx.x < 2){
    float acc = lb[threadIdx.x];
    #pragma unroll 4
    for (int k = 0; k < 192; ++k) acc += ft[k] * lw[k*2 + threadIdx.x];
    out[gr*2 + threadIdx.x] = acc;
  }
}

extern "C" void kernel_launch(void* const* d_in, const int* in_sizes, int n_in,
                              void* d_out, int out_size, void* d_ws, size_t ws_size,
                              hipStream_t stream) {
  const float* x    = (const float*)d_in[0];
  const int*   ei   = (const int*)d_in[1];
  const int*   batch= (const int*)d_in[2];
  const float* W1l  = (const float*)d_in[3];
  const float* b1l  = (const float*)d_in[4];
  const float* W1r  = (const float*)d_in[5];
  const float* b1r  = (const float*)d_in[6];
  const float* att1 = (const float*)d_in[7];
  const float* bias1= (const float*)d_in[8];
  const float* W2l  = (const float*)d_in[9];
  const float* b2l  = (const float*)d_in[10];
  const float* W2r  = (const float*)d_in[11];
  const float* b2r  = (const float*)d_in[12];
  const float* att2 = (const float*)d_in[13];
  const float* bias2= (const float*)d_in[14];
  const float* g1   = (const float*)d_in[15];
  const float* be1  = (const float*)d_in[16];
  const float* g2   = (const float*)d_in[17];
  const float* be2  = (const float*)d_in[18];
  const float* lw   = (const float*)d_in[19];
  const float* lb   = (const float*)d_in[20];

  const int N  = in_sizes[0] / 64;
  const int E  = in_sizes[1] / 2;
  const int EL = E + N;
  const int G  = 128;
  const int NB = (N + 127) >> BSHIFT;

  char* p = (char*)d_ws;
  auto carve = [&](size_t bytes)->char*{ char* r = p; p += (bytes + 255) & ~(size_t)255; return r; };
  // zero block: bfill(NB) + dh(512) + bn sums(384)
  int* zero   = (int*)carve((size_t)(NB + 512 + 384)*4);
  int* bfill  = zero;
  int* dh     = zero + NB;
  float* stats = (float*)(zero + NB + 512);
  float* bn1_sum = stats;
  float* bn1_sq  = stats + 128;
  float* bn2_sum = stats + 256;
  float* bn2_sq  = stats + 320;
  int* dfill  = (int*)carve((size_t)512*4);
  int* rstart = (int*)carve((size_t)N*4);
  int* rend   = (int*)carve((size_t)N*4);
  int* perm   = (int*)carve((size_t)N*4);
  unsigned* ebuf = (unsigned*)carve((size_t)NB*CAP*4);
  int* esrc   = (int*)carve((size_t)(NB*CAP + 1024)*4);   // +slack for unclamped pipeline reads
  __half* xl1 = (__half*)carve((size_t)N*128*2);
  __half* xr1 = (__half*)carve((size_t)N*128*2);
  __half* h1  = (__half*)carve((size_t)N*128*2);
  __half* xl2 = xl1;                    // xl1 block dead after k_gat1; holds xl2 | xr2
  __half* xr2 = xl1 + (size_t)N*64;
  __half* h2  = xr1;                    // xr1 block dead after k_gat1

  hipMemsetAsync(zero, 0, (size_t)(NB + 512 + 384)*4, stream);

  const int bb = (EL + CHUNK - 1)/CHUNK;
  const int gb = (N + 31)/32;
  const int db = (N + 1023)/1024;
  // fused: bucket (bb blocks) | gemm1 (gb blocks) — independent work, one dispatch
  k_pre<<<bb + gb, 256, 0, stream>>>(ei, E, N, NB, bfill, ebuf,
                                     x, W1l, b1l, W1r, b1r, xl1, xr1, bb);
  k_fine<<<NB, 1024, 0, stream>>>(ebuf, bfill, N, NB, rstart, rend, esrc, dh);
  k_dscan<<<1, 512, 0, stream>>>(dh, dfill);
  k_dperm<<<db, 256, 0, stream>>>(rstart, rend, N, dfill, perm);

  const int nb1 = ((N + 3)/4*64 + 255)/256;   // 4 nodes per wave
  const int nb2 = ((N + 7)/8*64 + 255)/256;   // 8 nodes per wave
  k_gat1<<<nb1, 256, 0, stream>>>(xl1, xr1, rstart, rend, esrc, perm, att1, bias1, h1, N);
  k_bnstats<128><<<256, 256, 0, stream>>>(h1, N, bn1_sum, bn1_sq);
  k_gemm2<<<gb, 256, 0, stream>>>((const __half2*)h1, W2l, b2l, W2r, b2r, xl2, xr2, N,
                                  bn1_sum, bn1_sq, g1, be1);
  k_gat2<<<nb2, 256, 0, stream>>>(xl2, xr2, rstart, rend, esrc, perm, att2, bias2, h2, N);
  k_bnstats<64><<<256, 256, 0, stream>>>(h2, N, bn2_sum, bn2_sq);
  k_pool<<<G, 256, 0, stream>>>(h2, batch, N, bn2_sum, bn2_sq, g2, be2, lw, lb, (float*)d_out);
}

// Round 14
// 368.060 us; speedup vs baseline: 1.6062x; 1.3147x over previous
//
#include <hip/hip_runtime.h>
#include <hip/hip_fp16.h>
#include <math.h>

#define BSHIFT 7          // 128 dst-nodes per bucket (requires N < 65536 for 16-bit packing)
#define CHUNK  8192       // edges per bucketing block
#define CAP    6144       // padded edge capacity per bucket (mean 4224, +29 sigma)

__device__ inline __half2 habs2_(__half2 x){
  union { __half2 h; unsigned u; } c; c.h = x; c.u &= 0x7FFF7FFFu; return c.h;
}
// lrelu(x) = 0.6x + 0.4|x|  (slope 0.2)
__device__ inline __half2 lrelu2_(__half2 x, __half2 c06, __half2 c04){
  return __hfma2(c04, habs2_(x), __hmul2(c06, x));
}

// ---------------- fused: bucket scatter (blocks < bb) | gemm1 64->2x128 fp16 (blocks >= bb) ----------------
__global__ __launch_bounds__(256) void k_pre(const int* __restrict__ ei, int E, int N, int NB,
    int* __restrict__ bfill, unsigned* __restrict__ ebuf,
    const float* __restrict__ X,
    const float* __restrict__ Wl, const float* __restrict__ bl,
    const float* __restrict__ Wr, const float* __restrict__ br,
    __half* __restrict__ outl, __half* __restrict__ outr, int bb){
  __shared__ float xs[32][64];           // 8KB; bucket path aliases it as int hist[]
  if ((int)blockIdx.x < bb){
    int* hist = (int*)&xs[0][0];
    int base = blockIdx.x*CHUNK;
    int EL = E + N;
    int end = min(base + CHUNK, EL);
    for (int i = threadIdx.x; i < NB; i += 256) hist[i] = 0;
    __syncthreads();
    for (int e = base + threadIdx.x; e < end; e += 256){
      int d = (e < E) ? ei[E + e] : (e - E);
      atomicAdd(&hist[d >> BSHIFT], 1);
    }
    __syncthreads();
    for (int b = threadIdx.x; b < NB; b += 256){
      int c = hist[b];
      hist[b] = (c > 0) ? (b*CAP + atomicAdd(&bfill[b], c)) : 0;
    }
    __syncthreads();
    for (int e = base + threadIdx.x; e < end; e += 256){
      int s, d;
      if (e < E){ s = ei[e]; d = ei[E + e]; } else { s = d = e - E; }
      int pos = atomicAdd(&hist[d >> BSHIFT], 1);
      ebuf[pos] = (unsigned)s | ((unsigned)d << 16);
    }
  } else {
    const int tid = threadIdx.x;
    const int n0 = ((int)blockIdx.x - bb)*32;
    for (int t = tid; t < 32*64; t += 256){
      int r = t >> 6, c = t & 63;
      int node = n0 + r;
      xs[r][c] = (node < N) ? X[(size_t)node*64 + c] : 0.f;
    }
    __syncthreads();
    const int jg = tid & 63;
    const int ng = tid >> 6;
    const int q  = jg*4;
    const bool isL = (q < 128);
    const float* W = isL ? Wl : Wr;
    const int jj   = isL ? q : q - 128;
    const float* bbp = isL ? bl : br;
    __half* OUT    = isL ? outl : outr;
    const float4 bias4 = *(const float4*)(bbp + jj);
    float acc[8][4];
    #pragma unroll
    for (int n = 0; n < 8; ++n){ acc[n][0]=acc[n][1]=acc[n][2]=acc[n][3]=0.f; }
    for (int k = 0; k < 64; k += 4){
      const float4 w0 = *(const float4*)(W + (size_t)(k+0)*128 + jj);
      const float4 w1 = *(const float4*)(W + (size_t)(k+1)*128 + jj);
      const float4 w2 = *(const float4*)(W + (size_t)(k+2)*128 + jj);
      const float4 w3 = *(const float4*)(W + (size_t)(k+3)*128 + jj);
      #pragma unroll
      for (int n = 0; n < 8; ++n){
        const float4 xv = *(const float4*)(&xs[ng*8 + n][k]);
        acc[n][0] = fmaf(xv.w,w3.x, fmaf(xv.z,w2.x, fmaf(xv.y,w1.x, fmaf(xv.x,w0.x, acc[n][0]))));
        acc[n][1] = fmaf(xv.w,w3.y, fmaf(xv.z,w2.y, fmaf(xv.y,w1.y, fmaf(xv.x,w0.y, acc[n][1]))));
        acc[n][2] = fmaf(xv.w,w3.z, fmaf(xv.z,w2.z, fmaf(xv.y,w1.z, fmaf(xv.x,w0.z, acc[n][2]))));
        acc[n][3] = fmaf(xv.w,w3.w, fmaf(xv.z,w2.w, fmaf(xv.y,w1.w, fmaf(xv.x,w0.w, acc[n][3]))));
      }
    }
    #pragma unroll
    for (int n = 0; n < 8; ++n){
      int node = n0 + ng*8 + n;
      if (node < N){
        union { __half2 h[2]; uint2 u; } cv;
        cv.h[0] = __floats2half2_rn(acc[n][0]+bias4.x, acc[n][1]+bias4.y);
        cv.h[1] = __floats2half2_rn(acc[n][2]+bias4.z, acc[n][3]+bias4.w);
        *(uint2*)(OUT + (size_t)node*128 + jj) = cv.u;
      }
    }
  }
}

// per-bucket: per-node counts, LDS scan -> rstart/rend, place edges. 1024 thr (latency).
// NOTE: no global histogram here — round 12/13 showed 50k direct global atomics into
// ~40 hot bins costs ~130us (cross-XCD serialization). Degree sort abandoned (net-neutral).
__global__ __launch_bounds__(1024) void k_fine(const unsigned* __restrict__ ebuf,
    const int* __restrict__ bfill, int N, int NB,
    int* __restrict__ rstart, int* __restrict__ rend, int* __restrict__ esrc){
  __shared__ int cnt[128];
  __shared__ int sc[128];
  __shared__ int base[128];
  int b = blockIdx.x;
  int n0 = b << BSHIFT;
  int nn = min(128, N - n0);
  int e0 = b*CAP;
  int e1 = e0 + bfill[b];
  if (threadIdx.x < 128) cnt[threadIdx.x] = 0;
  __syncthreads();
  for (int e = e0 + threadIdx.x; e < e1; e += 1024)
    atomicAdd(&cnt[(ebuf[e] >> 16) & 127], 1);
  __syncthreads();
  if (threadIdx.x < 128) sc[threadIdx.x] = cnt[threadIdx.x];
  __syncthreads();
  for (int off = 1; off < 128; off <<= 1){
    int v = 0;
    if (threadIdx.x < 128 && (int)threadIdx.x >= off) v = sc[threadIdx.x - off];
    __syncthreads();
    if (threadIdx.x < 128) sc[threadIdx.x] += v;
    __syncthreads();
  }
  if (threadIdx.x < 128){
    int bs = e0 + sc[threadIdx.x] - cnt[threadIdx.x];
    base[threadIdx.x] = bs;
    if ((int)threadIdx.x < nn){
      rstart[n0 + threadIdx.x] = bs;
      rend[n0 + threadIdx.x]   = bs + cnt[threadIdx.x];
    }
    cnt[threadIdx.x] = 0;
  }
  __syncthreads();
  for (int e = e0 + threadIdx.x; e < e1; e += 1024){
    unsigned pk = ebuf[e];
    int local = (int)(pk >> 16) & 127;
    int pos = base[local] + atomicAdd(&cnt[local], 1);
    esrc[pos] = (int)(pk & 0xffffu);
  }
}

// ---------------- gemm2 (128 -> 2x64 fp16), BN-affine (from raw sums) on fp16 input ----------------
__global__ __launch_bounds__(256) void k_gemm2(const __half2* __restrict__ X2,
    const float* __restrict__ Wl, const float* __restrict__ bl,
    const float* __restrict__ Wr, const float* __restrict__ br,
    __half* __restrict__ outl, __half* __restrict__ outr, int N,
    const float* __restrict__ bsum, const float* __restrict__ bsq,
    const float* __restrict__ gam, const float* __restrict__ bet){
  __shared__ float xs[32][128];
  const int tid = threadIdx.x;
  const int n0 = blockIdx.x*32;
  const float invN = 1.f/(float)N;
  for (int t = tid; t < 32*64; t += 256){
    int r = t >> 6, c2 = t & 63, c = c2*2;
    int node = n0 + r;
    float2 v = (node < N) ? __half22float2(X2[(size_t)node*64 + c2]) : make_float2(0.f,0.f);
    float m0 = bsum[c]*invN,   m1 = bsum[c+1]*invN;
    float r0 = rsqrtf(bsq[c]*invN   - m0*m0 + 1e-5f);
    float r1 = rsqrtf(bsq[c+1]*invN - m1*m1 + 1e-5f);
    v.x = (v.x - m0) * r0 * gam[c  ] + bet[c  ];
    v.y = (v.y - m1) * r1 * gam[c+1] + bet[c+1];
    xs[r][c] = v.x; xs[r][c+1] = v.y;
  }
  __syncthreads();
  const int jg = tid & 31;
  const int ng = tid >> 5;
  const int q  = jg*4;
  const bool isL = (q < 64);
  const float* W = isL ? Wl : Wr;
  const int jj   = isL ? q : q - 64;
  const float* bbp = isL ? bl : br;
  __half* OUT    = isL ? outl : outr;
  const float4 bias4 = *(const float4*)(bbp + jj);
  float acc[4][4];
  #pragma unroll
  for (int n = 0; n < 4; ++n){ acc[n][0]=acc[n][1]=acc[n][2]=acc[n][3]=0.f; }
  for (int k = 0; k < 128; k += 4){
    const float4 w0 = *(const float4*)(W + (size_t)(k+0)*64 + jj);
    const float4 w1 = *(const float4*)(W + (size_t)(k+1)*64 + jj);
    const float4 w2 = *(const float4*)(W + (size_t)(k+2)*64 + jj);
    const float4 w3 = *(const float4*)(W + (size_t)(k+3)*64 + jj);
    #pragma unroll
    for (int n = 0; n < 4; ++n){
      const float4 xv = *(const float4*)(&xs[ng*4 + n][k]);
      acc[n][0] = fmaf(xv.w,w3.x, fmaf(xv.z,w2.x, fmaf(xv.y,w1.x, fmaf(xv.x,w0.x, acc[n][0]))));
      acc[n][1] = fmaf(xv.w,w3.y, fmaf(xv.z,w2.y, fmaf(xv.y,w1.y, fmaf(xv.x,w0.y, acc[n][1]))));
      acc[n][2] = fmaf(xv.w,w3.z, fmaf(xv.z,w2.z, fmaf(xv.y,w1.z, fmaf(xv.x,w0.z, acc[n][2]))));
      acc[n][3] = fmaf(xv.w,w3.w, fmaf(xv.z,w2.w, fmaf(xv.y,w1.w, fmaf(xv.x,w0.w, acc[n][3]))));
    }
  }
  #pragma unroll
  for (int n = 0; n < 4; ++n){
    int node = n0 + ng*4 + n;
    if (node < N){
      union { __half2 h[2]; uint2 u; } cv;
      cv.h[0] = __floats2half2_rn(acc[n][0]+bias4.x, acc[n][1]+bias4.y);
      cv.h[1] = __floats2half2_rn(acc[n][2]+bias4.z, acc[n][3]+bias4.w);
      *(uint2*)(OUT + (size_t)node*64 + jj) = cv.u;
    }
  }
}

// ---------------- GAT layer 1: 4 nodes/wave, 16 lanes/node, rotated batch-4 gather pipeline ----------------
__global__ __launch_bounds__(256, 6) void k_gat1(const __half* __restrict__ xl, const __half* __restrict__ xr,
    const int* __restrict__ rstart, const int* __restrict__ rend,
    const int* __restrict__ esrc,
    const float* __restrict__ att, const float* __restrict__ bias,
    __half* __restrict__ h1, int N){
  int wv = (blockIdx.x*256 + threadIdx.x) >> 6;
  int lane = threadIdx.x & 63;
  int g = lane >> 4;
  int t = lane & 15;
  int node = wv*4 + g;
  bool live = node < N;
  int nd = live ? node : 0;
  int c0 = t*8;
  const __half2 c06 = __float2half2_rn(0.6f);
  const __half2 c04 = __float2half2_rn(0.4f);
  union { uint4 u; __half2 h[4]; } xru;
  xru.u = *(const uint4*)(xr + (size_t)nd*128 + c0);
  float4 a0 = *(const float4*)(att + c0);
  float4 a1 = *(const float4*)(att + c0 + 4);
  __half2 av2[4] = { __floats2half2_rn(a0.x,a0.y), __floats2half2_rn(a0.z,a0.w),
                     __floats2half2_rn(a1.x,a1.y), __floats2half2_rn(a1.z,a1.w) };
  int r0 = live ? rstart[nd] : 0;
  int r1 = live ? rend[nd]   : 0;
  int d  = r1 - r0;
  d = max(d, __shfl_xor(d, 16));
  d = max(d, __shfl_xor(d, 32));
  const char* xb = (const char*)xl;
  const unsigned cb = (unsigned)(c0*2);
  float s = 0.f;
  __half2 acc2[4];
  #pragma unroll
  for (int k = 0; k < 4; ++k) acc2[k] = __float2half2_rn(0.f);
  union V { uint4 u; __half2 h[4]; } cur[4], nxt[4];
  #pragma unroll
  for (int q = 0; q < 4; ++q){
    unsigned j = (unsigned)esrc[r0 + q] & 0xFFFFu;   // unclamped (esrc slack); gathers stay in fp16 ws; w masks validity
    cur[q].u = *(const uint4*)(xb + ((j << 8) + cb));
  }
  for (int i = 0; i < d; i += 4){
    #pragma unroll
    for (int q = 0; q < 4; ++q){
      unsigned j = (unsigned)esrc[r0 + i + 4 + q] & 0xFFFFu;
      nxt[q].u = *(const uint4*)(xb + ((j << 8) + cb));
    }
    #pragma unroll
    for (int q = 0; q < 4; ++q){
      bool valid = (r0 + i + q) < r1;
      __half2 p2 = __float2half2_rn(0.f);
      #pragma unroll
      for (int k = 0; k < 4; ++k){
        __half2 m2 = __hadd2(cur[q].h[k], xru.h[k]);
        p2 = __hfma2(lrelu2_(m2, c06, c04), av2[k], p2);
      }
      float p = __low2float(p2) + __high2float(p2);
      p += __shfl_xor(p, 1);
      p += __shfl_xor(p, 2);
      float w = valid ? __expf(p) : 0.f;
      s += w;
      __half2 w2 = __float2half2_rn(w);
      #pragma unroll
      for (int k = 0; k < 4; ++k) acc2[k] = __hfma2(w2, cur[q].h[k], acc2[k]);
    }
    #pragma unroll
    for (int q = 0; q < 4; ++q) cur[q] = nxt[q];
  }
  if (live){
    float inv = 1.f/s;
    float4 b0 = *(const float4*)(bias + c0);
    float4 b1 = *(const float4*)(bias + c0 + 4);
    float bv[8] = {b0.x,b0.y,b0.z,b0.w,b1.x,b1.y,b1.z,b1.w};
    union { __half2 h[4]; uint4 u; } o;
    #pragma unroll
    for (int k = 0; k < 4; ++k){
      float2 af = __half22float2(acc2[k]);
      float f0 = fmaxf(af.x*inv + bv[2*k],   0.f);
      float f1 = fmaxf(af.y*inv + bv[2*k+1], 0.f);
      o.h[k] = __floats2half2_rn(f0, f1);
    }
    *(uint4*)(h1 + (size_t)nd*128 + c0) = o.u;
  }
}

// ---------------- GAT layer 2: 8 nodes/wave, 8 lanes/node, rotated batch-4 gather pipeline ----------------
__global__ __launch_bounds__(256, 6) void k_gat2(const __half* __restrict__ xl, const __half* __restrict__ xr,
    const int* __restrict__ rstart, const int* __restrict__ rend,
    const int* __restrict__ esrc,
    const float* __restrict__ att, const float* __restrict__ bias,
    __half* __restrict__ h2, int N){
  int wv = (blockIdx.x*256 + threadIdx.x) >> 6;
  int lane = threadIdx.x & 63;
  int g = lane >> 3;
  int t = lane & 7;
  int node = wv*8 + g;
  bool live = node < N;
  int nd = live ? node : 0;
  int c0 = t*8;
  const __half2 c06 = __float2half2_rn(0.6f);
  const __half2 c04 = __float2half2_rn(0.4f);
  union { uint4 u; __half2 h[4]; } xru;
  xru.u = *(const uint4*)(xr + (size_t)nd*64 + c0);
  float4 a0 = *(const float4*)(att + c0);
  float4 a1 = *(const float4*)(att + c0 + 4);
  __half2 av2[4] = { __floats2half2_rn(a0.x,a0.y), __floats2half2_rn(a0.z,a0.w),
                     __floats2half2_rn(a1.x,a1.y), __floats2half2_rn(a1.z,a1.w) };
  int r0 = live ? rstart[nd] : 0;
  int r1 = live ? rend[nd]   : 0;
  int d  = r1 - r0;
  d = max(d, __shfl_xor(d, 8));
  d = max(d, __shfl_xor(d, 16));
  d = max(d, __shfl_xor(d, 32));
  const char* xb = (const char*)xl;
  const unsigned cb = (unsigned)(c0*2);
  float s = 0.f;
  __half2 acc2[4];
  #pragma unroll
  for (int k = 0; k < 4; ++k) acc2[k] = __float2half2_rn(0.f);
  union V { uint4 u; __half2 h[4]; } cur[4], nxt[4];
  #pragma unroll
  for (int q = 0; q < 4; ++q){
    unsigned j = (unsigned)esrc[r0 + q] & 0xFFFFu;
    cur[q].u = *(const uint4*)(xb + ((j << 7) + cb));
  }
  for (int i = 0; i < d; i += 4){
    #pragma unroll
    for (int q = 0; q < 4; ++q){
      unsigned j = (unsigned)esrc[r0 + i + 4 + q] & 0xFFFFu;
      nxt[q].u = *(const uint4*)(xb + ((j << 7) + cb));
    }
    #pragma unroll
    for (int q = 0; q < 4; ++q){
      bool valid = (r0 + i + q) < r1;
      __half2 p2 = __float2half2_rn(0.f);
      #pragma unroll
      for (int k = 0; k < 4; ++k){
        __half2 m2 = __hadd2(cur[q].h[k], xru.h[k]);
        p2 = __hfma2(lrelu2_(m2, c06, c04), av2[k], p2);
      }
      float p = __low2float(p2) + __high2float(p2);
      p += __shfl_xor(p, 1);
      p += __shfl_xor(p, 2);
      p += __shfl_xor(p, 4);
      float w = valid ? __expf(p) : 0.f;
      s += w;
      __half2 w2 = __float2half2_rn(w);
      #pragma unroll
      for (int k = 0; k < 4; ++k) acc2[k] = __hfma2(w2, cur[q].h[k], acc2[k]);
    }
    #pragma unroll
    for (int q = 0; q < 4; ++q) cur[q] = nxt[q];
  }
  if (live){
    float inv = 1.f/s;
    float4 b0 = *(const float4*)(bias + c0);
    float4 b1 = *(const float4*)(bias + c0 + 4);
    float bv[8] = {b0.x,b0.y,b0.z,b0.w,b1.x,b1.y,b1.z,b1.w};
    union { __half2 h[4]; uint4 u; } o;
    #pragma unroll
    for (int k = 0; k < 4; ++k){
      float2 af = __half22float2(acc2[k]);
      float f0 = fmaxf(af.x*inv + bv[2*k],   0.f);
      float f1 = fmaxf(af.y*inv + bv[2*k+1], 0.f);
      o.h[k] = __floats2half2_rn(f0, f1);
    }
    *(uint4*)(h2 + (size_t)nd*64 + c0) = o.u;
  }
}

// ---------------- BN stats over fp16 activations ----------------
template<int C>
__global__ __launch_bounds__(256) void k_bnstats(const __half* __restrict__ h, int N,
    float* __restrict__ sum, float* __restrict__ sq){
  constexpr int RPB = 256/C;
  int c = threadIdx.x % C;
  int sub = threadIdx.x / C;
  float s = 0.f, q = 0.f;
  for (int r = blockIdx.x*RPB + sub; r < N; r += gridDim.x*RPB){
    float v = __half2float(h[(size_t)r*C + c]);
    s += v; q += v*v;
  }
  __shared__ float ls[256], lq[256];
  ls[threadIdx.x] = s; lq[threadIdx.x] = q;
  __syncthreads();
  if (threadIdx.x < C){
    float S = ls[c], Q = lq[c];
    #pragma unroll
    for (int u = 1; u < RPB; ++u){ S += ls[u*C + c]; Q += lq[u*C + c]; }
    atomicAdd(&sum[c], S);
    atomicAdd(&sq[c], Q);
  }
}

// ---------------- pooling + head fused: BN2 final inline, writes d_out directly ----------------
__global__ __launch_bounds__(256) void k_pool(const __half* __restrict__ h2, const int* __restrict__ batch, int N,
    const float* __restrict__ bsum, const float* __restrict__ bsq,
    const float* __restrict__ g, const float* __restrict__ b,
    const float* __restrict__ lw, const float* __restrict__ lb,
    float* __restrict__ out){
  int gr = blockIdx.x;
  int lo = 0, hi = N;
  while (lo < hi){ int mid = (lo+hi)>>1; if (batch[mid] < gr) lo = mid+1; else hi = mid; }
  int r0 = lo;
  lo = r0; hi = N;
  while (lo < hi){ int mid = (lo+hi)>>1; if (batch[mid] < gr+1) lo = mid+1; else hi = mid; }
  int r1 = lo;
  int c = threadIdx.x & 63;
  int sub = threadIdx.x >> 6;
  const float invN = 1.f/(float)N;
  float m = bsum[c]*invN;
  float rs = rsqrtf(bsq[c]*invN - m*m + 1e-5f);
  float aff_s = rs*g[c];
  float aff_b = b[c] - m*aff_s;
  float s = 0.f, mx = -INFINITY;
  for (int r = r0 + sub; r < r1; r += 4){
    float v = __half2float(h2[(size_t)r*64 + c])*aff_s + aff_b;
    s += v; mx = fmaxf(mx, v);
  }
  __shared__ float ls[256], lm[256], ft[192];
  ls[threadIdx.x] = s; lm[threadIdx.x] = mx;
  __syncthreads();
  if (threadIdx.x < 64){
    float S = ls[c] + ls[64+c] + ls[128+c] + ls[192+c];
    float M = fmaxf(fmaxf(lm[c], lm[64+c]), fmaxf(lm[128+c], lm[192+c]));
    float cnt = (float)max(r1 - r0, 1);
    ft[c]       = S;
    ft[64 + c]  = S/cnt;
    ft[128 + c] = M;
  }
  __syncthreads();
  if (threadIdx.x < 2){
    float acc = lb[threadIdx.x];
    #pragma unroll 4
    for (int k = 0; k < 192; ++k) acc += ft[k] * lw[k*2 + threadIdx.x];
    out[gr*2 + threadIdx.x] = acc;
  }
}

extern "C" void kernel_launch(void* const* d_in, const int* in_sizes, int n_in,
                              void* d_out, int out_size, void* d_ws, size_t ws_size,
                              hipStream_t stream) {
  const float* x    = (const float*)d_in[0];
  const int*   ei   = (const int*)d_in[1];
  const int*   batch= (const int*)d_in[2];
  const float* W1l  = (const float*)d_in[3];
  const float* b1l  = (const float*)d_in[4];
  const float* W1r  = (const float*)d_in[5];
  const float* b1r  = (const float*)d_in[6];
  const float* att1 = (const float*)d_in[7];
  const float* bias1= (const float*)d_in[8];
  const float* W2l  = (const float*)d_in[9];
  const float* b2l  = (const float*)d_in[10];
  const float* W2r  = (const float*)d_in[11];
  const float* b2r  = (const float*)d_in[12];
  const float* att2 = (const float*)d_in[13];
  const float* bias2= (const float*)d_in[14];
  const float* g1   = (const float*)d_in[15];
  const float* be1  = (const float*)d_in[16];
  const float* g2   = (const float*)d_in[17];
  const float* be2  = (const float*)d_in[18];
  const float* lw   = (const float*)d_in[19];
  const float* lb   = (const float*)d_in[20];

  const int N  = in_sizes[0] / 64;
  const int E  = in_sizes[1] / 2;
  const int EL = E + N;
  const int G  = 128;
  const int NB = (N + 127) >> BSHIFT;

  char* p = (char*)d_ws;
  auto carve = [&](size_t bytes)->char*{ char* r = p; p += (bytes + 255) & ~(size_t)255; return r; };
  // zero block: bfill(NB) + bn sums(384)
  int* zero   = (int*)carve((size_t)(NB + 384)*4);
  int* bfill  = zero;
  float* stats = (float*)(zero + NB);
  float* bn1_sum = stats;
  float* bn1_sq  = stats + 128;
  float* bn2_sum = stats + 256;
  float* bn2_sq  = stats + 320;
  int* rstart = (int*)carve((size_t)N*4);
  int* rend   = (int*)carve((size_t)N*4);
  unsigned* ebuf = (unsigned*)carve((size_t)NB*CAP*4);
  int* esrc   = (int*)carve((size_t)(NB*CAP + 1024)*4);   // +slack for unclamped pipeline reads
  __half* xl1 = (__half*)carve((size_t)N*128*2);
  __half* xr1 = (__half*)carve((size_t)N*128*2);
  __half* h1  = (__half*)carve((size_t)N*128*2);
  __half* xl2 = xl1;                    // xl1 block dead after k_gat1; holds xl2 | xr2
  __half* xr2 = xl1 + (size_t)N*64;
  __half* h2  = xr1;                    // xr1 block dead after k_gat1

  hipMemsetAsync(zero, 0, (size_t)(NB + 384)*4, stream);

  const int bb = (EL + CHUNK - 1)/CHUNK;
  const int gb = (N + 31)/32;
  // fused: bucket (bb blocks) | gemm1 (gb blocks) — independent work, one dispatch
  k_pre<<<bb + gb, 256, 0, stream>>>(ei, E, N, NB, bfill, ebuf,
                                     x, W1l, b1l, W1r, b1r, xl1, xr1, bb);
  k_fine<<<NB, 1024, 0, stream>>>(ebuf, bfill, N, NB, rstart, rend, esrc);

  const int nb1 = ((N + 3)/4*64 + 255)/256;   // 4 nodes per wave
  const int nb2 = ((N + 7)/8*64 + 255)/256;   // 8 nodes per wave
  k_gat1<<<nb1, 256, 0, stream>>>(xl1, xr1, rstart, rend, esrc, att1, bias1, h1, N);
  k_bnstats<128><<<256, 256, 0, stream>>>(h1, N, bn1_sum, bn1_sq);
  k_gemm2<<<gb, 256, 0, stream>>>((const __half2*)h1, W2l, b2l, W2r, b2r, xl2, xr2, N,
                                  bn1_sum, bn1_sq, g1, be1);
  k_gat2<<<nb2, 256, 0, stream>>>(xl2, xr2, rstart, rend, esrc, att2, bias2, h2, N);
  k_bnstats<64><<<256, 256, 0, stream>>>(h2, N, bn2_sum, bn2_sq);
  k_pool<<<G, 256, 0, stream>>>(h2, batch, N, bn2_sum, bn2_sq, g2, be2, lw, lb, (float*)d_out);
}

// Round 15
// 360.858 us; speedup vs baseline: 1.6383x; 1.0200x over previous
//
#include <hip/hip_runtime.h>
#include <hip/hip_fp16.h>
#include <math.h>

#define BSHIFT 7          // 128 dst-nodes per bucket (requires N < 65536 for 16-bit packing)
#define CHUNK  8192       // edges per bucketing block
#define CAP    6144       // padded edge capacity per bucket (mean 4224, +29 sigma)

__device__ inline __half2 habs2_(__half2 x){
  union { __half2 h; unsigned u; } c; c.h = x; c.u &= 0x7FFF7FFFu; return c.h;
}
// lrelu(x) = 0.6x + 0.4|x|  (slope 0.2)
__device__ inline __half2 lrelu2_(__half2 x, __half2 c06, __half2 c04){
  return __hfma2(c04, habs2_(x), __hmul2(c06, x));
}

// ---------------- fused: bucket scatter (blocks < bb) | gemm1 64->2x128 fp16 (blocks >= bb) ----------------
__global__ __launch_bounds__(256) void k_pre(const int* __restrict__ ei, int E, int N, int NB,
    int* __restrict__ bfill, unsigned* __restrict__ ebuf,
    const float* __restrict__ X,
    const float* __restrict__ Wl, const float* __restrict__ bl,
    const float* __restrict__ Wr, const float* __restrict__ br,
    __half* __restrict__ outl, __half* __restrict__ outr, int bb){
  __shared__ float xs[32][64];           // 8KB; bucket path aliases it as int hist[]
  if ((int)blockIdx.x < bb){
    int* hist = (int*)&xs[0][0];
    int base = blockIdx.x*CHUNK;
    int EL = E + N;
    int end = min(base + CHUNK, EL);
    for (int i = threadIdx.x; i < NB; i += 256) hist[i] = 0;
    __syncthreads();
    for (int e = base + threadIdx.x; e < end; e += 256){
      int d = (e < E) ? ei[E + e] : (e - E);
      atomicAdd(&hist[d >> BSHIFT], 1);
    }
    __syncthreads();
    for (int b = threadIdx.x; b < NB; b += 256){
      int c = hist[b];
      hist[b] = (c > 0) ? (b*CAP + atomicAdd(&bfill[b], c)) : 0;
    }
    __syncthreads();
    for (int e = base + threadIdx.x; e < end; e += 256){
      int s, d;
      if (e < E){ s = ei[e]; d = ei[E + e]; } else { s = d = e - E; }
      int pos = atomicAdd(&hist[d >> BSHIFT], 1);
      ebuf[pos] = (unsigned)s | ((unsigned)d << 16);
    }
  } else {
    const int tid = threadIdx.x;
    const int n0 = ((int)blockIdx.x - bb)*32;
    for (int t = tid; t < 32*64; t += 256){
      int r = t >> 6, c = t & 63;
      int node = n0 + r;
      xs[r][c] = (node < N) ? X[(size_t)node*64 + c] : 0.f;
    }
    __syncthreads();
    const int jg = tid & 63;
    const int ng = tid >> 6;
    const int q  = jg*4;
    const bool isL = (q < 128);
    const float* W = isL ? Wl : Wr;
    const int jj   = isL ? q : q - 128;
    const float* bbp = isL ? bl : br;
    __half* OUT    = isL ? outl : outr;
    const float4 bias4 = *(const float4*)(bbp + jj);
    float acc[8][4];
    #pragma unroll
    for (int n = 0; n < 8; ++n){ acc[n][0]=acc[n][1]=acc[n][2]=acc[n][3]=0.f; }
    for (int k = 0; k < 64; k += 4){
      const float4 w0 = *(const float4*)(W + (size_t)(k+0)*128 + jj);
      const float4 w1 = *(const float4*)(W + (size_t)(k+1)*128 + jj);
      const float4 w2 = *(const float4*)(W + (size_t)(k+2)*128 + jj);
      const float4 w3 = *(const float4*)(W + (size_t)(k+3)*128 + jj);
      #pragma unroll
      for (int n = 0; n < 8; ++n){
        const float4 xv = *(const float4*)(&xs[ng*8 + n][k]);
        acc[n][0] = fmaf(xv.w,w3.x, fmaf(xv.z,w2.x, fmaf(xv.y,w1.x, fmaf(xv.x,w0.x, acc[n][0]))));
        acc[n][1] = fmaf(xv.w,w3.y, fmaf(xv.z,w2.y, fmaf(xv.y,w1.y, fmaf(xv.x,w0.y, acc[n][1]))));
        acc[n][2] = fmaf(xv.w,w3.z, fmaf(xv.z,w2.z, fmaf(xv.y,w1.z, fmaf(xv.x,w0.z, acc[n][2]))));
        acc[n][3] = fmaf(xv.w,w3.w, fmaf(xv.z,w2.w, fmaf(xv.y,w1.w, fmaf(xv.x,w0.w, acc[n][3]))));
      }
    }
    #pragma unroll
    for (int n = 0; n < 8; ++n){
      int node = n0 + ng*8 + n;
      if (node < N){
        union { __half2 h[2]; uint2 u; } cv;
        cv.h[0] = __floats2half2_rn(acc[n][0]+bias4.x, acc[n][1]+bias4.y);
        cv.h[1] = __floats2half2_rn(acc[n][2]+bias4.z, acc[n][3]+bias4.w);
        *(uint2*)(OUT + (size_t)node*128 + jj) = cv.u;
      }
    }
  }
}

// per-bucket: per-node counts, LDS scan -> rstart/rend, place edges. 1024 thr (latency).
__global__ __launch_bounds__(1024) void k_fine(const unsigned* __restrict__ ebuf,
    const int* __restrict__ bfill, int N, int NB,
    int* __restrict__ rstart, int* __restrict__ rend, int* __restrict__ esrc){
  __shared__ int cnt[128];
  __shared__ int sc[128];
  __shared__ int base[128];
  int b = blockIdx.x;
  int n0 = b << BSHIFT;
  int nn = min(128, N - n0);
  int e0 = b*CAP;
  int e1 = e0 + bfill[b];
  if (threadIdx.x < 128) cnt[threadIdx.x] = 0;
  __syncthreads();
  for (int e = e0 + threadIdx.x; e < e1; e += 1024)
    atomicAdd(&cnt[(ebuf[e] >> 16) & 127], 1);
  __syncthreads();
  if (threadIdx.x < 128) sc[threadIdx.x] = cnt[threadIdx.x];
  __syncthreads();
  for (int off = 1; off < 128; off <<= 1){
    int v = 0;
    if (threadIdx.x < 128 && (int)threadIdx.x >= off) v = sc[threadIdx.x - off];
    __syncthreads();
    if (threadIdx.x < 128) sc[threadIdx.x] += v;
    __syncthreads();
  }
  if (threadIdx.x < 128){
    int bs = e0 + sc[threadIdx.x] - cnt[threadIdx.x];
    base[threadIdx.x] = bs;
    if ((int)threadIdx.x < nn){
      rstart[n0 + threadIdx.x] = bs;
      rend[n0 + threadIdx.x]   = bs + cnt[threadIdx.x];
    }
    cnt[threadIdx.x] = 0;
  }
  __syncthreads();
  for (int e = e0 + threadIdx.x; e < e1; e += 1024){
    unsigned pk = ebuf[e];
    int local = (int)(pk >> 16) & 127;
    int pos = base[local] + atomicAdd(&cnt[local], 1);
    esrc[pos] = (int)(pk & 0xffffu);
  }
}

// ---------------- gemm2 (128 -> 2x64 fp16), BN-affine (from raw sums) on fp16 input ----------------
__global__ __launch_bounds__(256) void k_gemm2(const __half2* __restrict__ X2,
    const float* __restrict__ Wl, const float* __restrict__ bl,
    const float* __restrict__ Wr, const float* __restrict__ br,
    __half* __restrict__ outl, __half* __restrict__ outr, int N,
    const float* __restrict__ bsum, const float* __restrict__ bsq,
    const float* __restrict__ gam, const float* __restrict__ bet){
  __shared__ float xs[32][128];
  const int tid = threadIdx.x;
  const int n0 = blockIdx.x*32;
  const float invN = 1.f/(float)N;
  for (int t = tid; t < 32*64; t += 256){
    int r = t >> 6, c2 = t & 63, c = c2*2;
    int node = n0 + r;
    float2 v = (node < N) ? __half22float2(X2[(size_t)node*64 + c2]) : make_float2(0.f,0.f);
    float m0 = bsum[c]*invN,   m1 = bsum[c+1]*invN;
    float r0 = rsqrtf(bsq[c]*invN   - m0*m0 + 1e-5f);
    float r1 = rsqrtf(bsq[c+1]*invN - m1*m1 + 1e-5f);
    v.x = (v.x - m0) * r0 * gam[c  ] + bet[c  ];
    v.y = (v.y - m1) * r1 * gam[c+1] + bet[c+1];
    xs[r][c] = v.x; xs[r][c+1] = v.y;
  }
  __syncthreads();
  const int jg = tid & 31;
  const int ng = tid >> 5;
  const int q  = jg*4;
  const bool isL = (q < 64);
  const float* W = isL ? Wl : Wr;
  const int jj   = isL ? q : q - 64;
  const float* bbp = isL ? bl : br;
  __half* OUT    = isL ? outl : outr;
  const float4 bias4 = *(const float4*)(bbp + jj);
  float acc[4][4];
  #pragma unroll
  for (int n = 0; n < 4; ++n){ acc[n][0]=acc[n][1]=acc[n][2]=acc[n][3]=0.f; }
  for (int k = 0; k < 128; k += 4){
    const float4 w0 = *(const float4*)(W + (size_t)(k+0)*64 + jj);
    const float4 w1 = *(const float4*)(W + (size_t)(k+1)*64 + jj);
    const float4 w2 = *(const float4*)(W + (size_t)(k+2)*64 + jj);
    const float4 w3 = *(const float4*)(W + (size_t)(k+3)*64 + jj);
    #pragma unroll
    for (int n = 0; n < 4; ++n){
      const float4 xv = *(const float4*)(&xs[ng*4 + n][k]);
      acc[n][0] = fmaf(xv.w,w3.x, fmaf(xv.z,w2.x, fmaf(xv.y,w1.x, fmaf(xv.x,w0.x, acc[n][0]))));
      acc[n][1] = fmaf(xv.w,w3.y, fmaf(xv.z,w2.y, fmaf(xv.y,w1.y, fmaf(xv.x,w0.y, acc[n][1]))));
      acc[n][2] = fmaf(xv.w,w3.z, fmaf(xv.z,w2.z, fmaf(xv.y,w1.z, fmaf(xv.x,w0.z, acc[n][2]))));
      acc[n][3] = fmaf(xv.w,w3.w, fmaf(xv.z,w2.w, fmaf(xv.y,w1.w, fmaf(xv.x,w0.w, acc[n][3]))));
    }
  }
  #pragma unroll
  for (int n = 0; n < 4; ++n){
    int node = n0 + ng*4 + n;
    if (node < N){
      union { __half2 h[2]; uint2 u; } cv;
      cv.h[0] = __floats2half2_rn(acc[n][0]+bias4.x, acc[n][1]+bias4.y);
      cv.h[1] = __floats2half2_rn(acc[n][2]+bias4.z, acc[n][3]+bias4.w);
      *(uint2*)(OUT + (size_t)node*64 + jj) = cv.u;
    }
  }
}

// ---------------- GAT layer 1: 4 nodes/wave, 16 lanes/node, rotated batch-4 gather pipeline ----------------
// Pad-slot esrc reads are CLAMPED to r0 (hot line): unclamped junk gathers cost +28MB FETCH (round 14).
__global__ __launch_bounds__(256, 6) void k_gat1(const __half* __restrict__ xl, const __half* __restrict__ xr,
    const int* __restrict__ rstart, const int* __restrict__ rend,
    const int* __restrict__ esrc,
    const float* __restrict__ att, const float* __restrict__ bias,
    __half* __restrict__ h1, int N){
  int wv = (blockIdx.x*256 + threadIdx.x) >> 6;
  int lane = threadIdx.x & 63;
  int g = lane >> 4;
  int t = lane & 15;
  int node = wv*4 + g;
  bool live = node < N;
  int nd = live ? node : 0;
  int c0 = t*8;
  const __half2 c06 = __float2half2_rn(0.6f);
  const __half2 c04 = __float2half2_rn(0.4f);
  union { uint4 u; __half2 h[4]; } xru;
  xru.u = *(const uint4*)(xr + (size_t)nd*128 + c0);
  float4 a0 = *(const float4*)(att + c0);
  float4 a1 = *(const float4*)(att + c0 + 4);
  __half2 av2[4] = { __floats2half2_rn(a0.x,a0.y), __floats2half2_rn(a0.z,a0.w),
                     __floats2half2_rn(a1.x,a1.y), __floats2half2_rn(a1.z,a1.w) };
  int r0 = live ? rstart[nd] : 0;
  int r1 = live ? rend[nd]   : 0;
  int d  = r1 - r0;
  d = max(d, __shfl_xor(d, 16));
  d = max(d, __shfl_xor(d, 32));
  const char* xb = (const char*)xl;
  const unsigned cb = (unsigned)(c0*2);
  float s = 0.f;
  __half2 acc2[4];
  #pragma unroll
  for (int k = 0; k < 4; ++k) acc2[k] = __float2half2_rn(0.f);
  union V { uint4 u; __half2 h[4]; } cur[4], nxt[4];
  #pragma unroll
  for (int q = 0; q < 4; ++q){
    int e = r0 + q;
    unsigned j = (unsigned)esrc[e < r1 ? e : r0];
    cur[q].u = *(const uint4*)(xb + ((j << 8) + cb));
  }
  for (int i = 0; i < d; i += 4){
    #pragma unroll
    for (int q = 0; q < 4; ++q){
      int e = r0 + i + 4 + q;
      unsigned j = (unsigned)esrc[e < r1 ? e : r0];
      nxt[q].u = *(const uint4*)(xb + ((j << 8) + cb));
    }
    #pragma unroll
    for (int q = 0; q < 4; ++q){
      bool valid = (r0 + i + q) < r1;
      __half2 p2 = __float2half2_rn(0.f);
      #pragma unroll
      for (int k = 0; k < 4; ++k){
        __half2 m2 = __hadd2(cur[q].h[k], xru.h[k]);
        p2 = __hfma2(lrelu2_(m2, c06, c04), av2[k], p2);
      }
      float p = __low2float(p2) + __high2float(p2);
      p += __shfl_xor(p, 1);
      p += __shfl_xor(p, 2);
      float w = valid ? __expf(p) : 0.f;
      s += w;
      __half2 w2 = __float2half2_rn(w);
      #pragma unroll
      for (int k = 0; k < 4; ++k) acc2[k] = __hfma2(w2, cur[q].h[k], acc2[k]);
    }
    #pragma unroll
    for (int q = 0; q < 4; ++q) cur[q] = nxt[q];
  }
  if (live){
    float inv = 1.f/s;
    float4 b0 = *(const float4*)(bias + c0);
    float4 b1 = *(const float4*)(bias + c0 + 4);
    float bv[8] = {b0.x,b0.y,b0.z,b0.w,b1.x,b1.y,b1.z,b1.w};
    union { __half2 h[4]; uint4 u; } o;
    #pragma unroll
    for (int k = 0; k < 4; ++k){
      float2 af = __half22float2(acc2[k]);
      float f0 = fmaxf(af.x*inv + bv[2*k],   0.f);
      float f1 = fmaxf(af.y*inv + bv[2*k+1], 0.f);
      o.h[k] = __floats2half2_rn(f0, f1);
    }
    *(uint4*)(h1 + (size_t)nd*128 + c0) = o.u;
  }
}

// ---------------- GAT layer 2: 8 nodes/wave, 8 lanes/node, rotated batch-4 gather pipeline ----------------
__global__ __launch_bounds__(256, 6) void k_gat2(const __half* __restrict__ xl, const __half* __restrict__ xr,
    const int* __restrict__ rstart, const int* __restrict__ rend,
    const int* __restrict__ esrc,
    const float* __restrict__ att, const float* __restrict__ bias,
    __half* __restrict__ h2, int N){
  int wv = (blockIdx.x*256 + threadIdx.x) >> 6;
  int lane = threadIdx.x & 63;
  int g = lane >> 3;
  int t = lane & 7;
  int node = wv*8 + g;
  bool live = node < N;
  int nd = live ? node : 0;
  int c0 = t*8;
  const __half2 c06 = __float2half2_rn(0.6f);
  const __half2 c04 = __float2half2_rn(0.4f);
  union { uint4 u; __half2 h[4]; } xru;
  xru.u = *(const uint4*)(xr + (size_t)nd*64 + c0);
  float4 a0 = *(const float4*)(att + c0);
  float4 a1 = *(const float4*)(att + c0 + 4);
  __half2 av2[4] = { __floats2half2_rn(a0.x,a0.y), __floats2half2_rn(a0.z,a0.w),
                     __floats2half2_rn(a1.x,a1.y), __floats2half2_rn(a1.z,a1.w) };
  int r0 = live ? rstart[nd] : 0;
  int r1 = live ? rend[nd]   : 0;
  int d  = r1 - r0;
  d = max(d, __shfl_xor(d, 8));
  d = max(d, __shfl_xor(d, 16));
  d = max(d, __shfl_xor(d, 32));
  const char* xb = (const char*)xl;
  const unsigned cb = (unsigned)(c0*2);
  float s = 0.f;
  __half2 acc2[4];
  #pragma unroll
  for (int k = 0; k < 4; ++k) acc2[k] = __float2half2_rn(0.f);
  union V { uint4 u; __half2 h[4]; } cur[4], nxt[4];
  #pragma unroll
  for (int q = 0; q < 4; ++q){
    int e = r0 + q;
    unsigned j = (unsigned)esrc[e < r1 ? e : r0];
    cur[q].u = *(const uint4*)(xb + ((j << 7) + cb));
  }
  for (int i = 0; i < d; i += 4){
    #pragma unroll
    for (int q = 0; q < 4; ++q){
      int e = r0 + i + 4 + q;
      unsigned j = (unsigned)esrc[e < r1 ? e : r0];
      nxt[q].u = *(const uint4*)(xb + ((j << 7) + cb));
    }
    #pragma unroll
    for (int q = 0; q < 4; ++q){
      bool valid = (r0 + i + q) < r1;
      __half2 p2 = __float2half2_rn(0.f);
      #pragma unroll
      for (int k = 0; k < 4; ++k){
        __half2 m2 = __hadd2(cur[q].h[k], xru.h[k]);
        p2 = __hfma2(lrelu2_(m2, c06, c04), av2[k], p2);
      }
      float p = __low2float(p2) + __high2float(p2);
      p += __shfl_xor(p, 1);
      p += __shfl_xor(p, 2);
      p += __shfl_xor(p, 4);
      float w = valid ? __expf(p) : 0.f;
      s += w;
      __half2 w2 = __float2half2_rn(w);
      #pragma unroll
      for (int k = 0; k < 4; ++k) acc2[k] = __hfma2(w2, cur[q].h[k], acc2[k]);
    }
    #pragma unroll
    for (int q = 0; q < 4; ++q) cur[q] = nxt[q];
  }
  if (live){
    float inv = 1.f/s;
    float4 b0 = *(const float4*)(bias + c0);
    float4 b1 = *(const float4*)(bias + c0 + 4);
    float bv[8] = {b0.x,b0.y,b0.z,b0.w,b1.x,b1.y,b1.z,b1.w};
    union { __half2 h[4]; uint4 u; } o;
    #pragma unroll
    for (int k = 0; k < 4; ++k){
      float2 af = __half22float2(acc2[k]);
      float f0 = fmaxf(af.x*inv + bv[2*k],   0.f);
      float f1 = fmaxf(af.y*inv + bv[2*k+1], 0.f);
      o.h[k] = __floats2half2_rn(f0, f1);
    }
    *(uint4*)(h2 + (size_t)nd*64 + c0) = o.u;
  }
}

// ---------------- BN stats over fp16 activations ----------------
template<int C>
__global__ __launch_bounds__(256) void k_bnstats(const __half* __restrict__ h, int N,
    float* __restrict__ sum, float* __restrict__ sq){
  constexpr int RPB = 256/C;
  int c = threadIdx.x % C;
  int sub = threadIdx.x / C;
  float s = 0.f, q = 0.f;
  for (int r = blockIdx.x*RPB + sub; r < N; r += gridDim.x*RPB){
    float v = __half2float(h[(size_t)r*C + c]);
    s += v; q += v*v;
  }
  __shared__ float ls[256], lq[256];
  ls[threadIdx.x] = s; lq[threadIdx.x] = q;
  __syncthreads();
  if (threadIdx.x < C){
    float S = ls[c], Q = lq[c];
    #pragma unroll
    for (int u = 1; u < RPB; ++u){ S += ls[u*C + c]; Q += lq[u*C + c]; }
    atomicAdd(&sum[c], S);
    atomicAdd(&sq[c], Q);
  }
}

// ---------------- pooling + head fused: BN2 final inline, writes d_out directly ----------------
__global__ __launch_bounds__(256) void k_pool(const __half* __restrict__ h2, const int* __restrict__ batch, int N,
    const float* __restrict__ bsum, const float* __restrict__ bsq,
    const float* __restrict__ g, const float* __restrict__ b,
    const float* __restrict__ lw, const float* __restrict__ lb,
    float* __restrict__ out){
  int gr = blockIdx.x;
  int lo = 0, hi = N;
  while (lo < hi){ int mid = (lo+hi)>>1; if (batch[mid] < gr) lo = mid+1; else hi = mid; }
  int r0 = lo;
  lo = r0; hi = N;
  while (lo < hi){ int mid = (lo+hi)>>1; if (batch[mid] < gr+1) lo = mid+1; else hi = mid; }
  int r1 = lo;
  int c = threadIdx.x & 63;
  int sub = threadIdx.x >> 6;
  const float invN = 1.f/(float)N;
  float m = bsum[c]*invN;
  float rs = rsqrtf(bsq[c]*invN - m*m + 1e-5f);
  float aff_s = rs*g[c];
  float aff_b = b[c] - m*aff_s;
  float s = 0.f, mx = -INFINITY;
  for (int r = r0 + sub; r < r1; r += 4){
    float v = __half2float(h2[(size_t)r*64 + c])*aff_s + aff_b;
    s += v; mx = fmaxf(mx, v);
  }
  __shared__ float ls[256], lm[256], ft[192];
  ls[threadIdx.x] = s; lm[threadIdx.x] = mx;
  __syncthreads();
  if (threadIdx.x < 64){
    float S = ls[c] + ls[64+c] + ls[128+c] + ls[192+c];
    float M = fmaxf(fmaxf(lm[c], lm[64+c]), fmaxf(lm[128+c], lm[192+c]));
    float cnt = (float)max(r1 - r0, 1);
    ft[c]       = S;
    ft[64 + c]  = S/cnt;
    ft[128 + c] = M;
  }
  __syncthreads();
  if (threadIdx.x < 2){
    float acc = lb[threadIdx.x];
    #pragma unroll 4
    for (int k = 0; k < 192; ++k) acc += ft[k] * lw[k*2 + threadIdx.x];
    out[gr*2 + threadIdx.x] = acc;
  }
}

extern "C" void kernel_launch(void* const* d_in, const int* in_sizes, int n_in,
                              void* d_out, int out_size, void* d_ws, size_t ws_size,
                              hipStream_t stream) {
  const float* x    = (const float*)d_in[0];
  const int*   ei   = (const int*)d_in[1];
  const int*   batch= (const int*)d_in[2];
  const float* W1l  = (const float*)d_in[3];
  const float* b1l  = (const float*)d_in[4];
  const float* W1r  = (const float*)d_in[5];
  const float* b1r  = (const float*)d_in[6];
  const float* att1 = (const float*)d_in[7];
  const float* bias1= (const float*)d_in[8];
  const float* W2l  = (const float*)d_in[9];
  const float* b2l  = (const float*)d_in[10];
  const float* W2r  = (const float*)d_in[11];
  const float* b2r  = (const float*)d_in[12];
  const float* att2 = (const float*)d_in[13];
  const float* bias2= (const float*)d_in[14];
  const float* g1   = (const float*)d_in[15];
  const float* be1  = (const float*)d_in[16];
  const float* g2   = (const float*)d_in[17];
  const float* be2  = (const float*)d_in[18];
  const float* lw   = (const float*)d_in[19];
  const float* lb   = (const float*)d_in[20];

  const int N  = in_sizes[0] / 64;
  const int E  = in_sizes[1] / 2;
  const int EL = E + N;
  const int G  = 128;
  const int NB = (N + 127) >> BSHIFT;

  char* p = (char*)d_ws;
  auto carve = [&](size_t bytes)->char*{ char* r = p; p += (bytes + 255) & ~(size_t)255; return r; };
  // zero block: bfill(NB) + bn sums(384)
  int* zero   = (int*)carve((size_t)(NB + 384)*4);
  int* bfill  = zero;
  float* stats = (float*)(zero + NB);
  float* bn1_sum = stats;
  float* bn1_sq  = stats + 128;
  float* bn2_sum = stats + 256;
  float* bn2_sq  = stats + 320;
  int* rstart = (int*)carve((size_t)N*4);
  int* rend   = (int*)carve((size_t)N*4);
  unsigned* ebuf = (unsigned*)carve((size_t)NB*CAP*4);
  int* esrc   = (int*)carve((size_t)(NB*CAP + 1024)*4);
  __half* xl1 = (__half*)carve((size_t)N*128*2);
  __half* xr1 = (__half*)carve((size_t)N*128*2);
  __half* h1  = (__half*)carve((size_t)N*128*2);
  __half* xl2 = xl1;                    // xl1 block dead after k_gat1; holds xl2 | xr2
  __half* xr2 = xl1 + (size_t)N*64;
  __half* h2  = xr1;                    // xr1 block dead after k_gat1

  hipMemsetAsync(zero, 0, (size_t)(NB + 384)*4, stream);

  const int bb = (EL + CHUNK - 1)/CHUNK;
  const int gb = (N + 31)/32;
  // fused: bucket (bb blocks) | gemm1 (gb blocks) — independent work, one dispatch
  k_pre<<<bb + gb, 256, 0, stream>>>(ei, E, N, NB, bfill, ebuf,
                                     x, W1l, b1l, W1r, b1r, xl1, xr1, bb);
  k_fine<<<NB, 1024, 0, stream>>>(ebuf, bfill, N, NB, rstart, rend, esrc);

  const int nb1 = ((N + 3)/4*64 + 255)/256;   // 4 nodes per wave
  const int nb2 = ((N + 7)/8*64 + 255)/256;   // 8 nodes per wave
  k_gat1<<<nb1, 256, 0, stream>>>(xl1, xr1, rstart, rend, esrc, att1, bias1, h1, N);
  k_bnstats<128><<<256, 256, 0, stream>>>(h1, N, bn1_sum, bn1_sq);
  k_gemm2<<<gb, 256, 0, stream>>>((const __half2*)h1, W2l, b2l, W2r, b2r, xl2, xr2, N,
                                  bn1_sum, bn1_sq, g1, be1);
  k_gat2<<<nb2, 256, 0, stream>>>(xl2, xr2, rstart, rend, esrc, att2, bias2, h2, N);
  k_bnstats<64><<<256, 256, 0, stream>>>(h2, N, bn2_sum, bn2_sq);
  k_pool<<<G, 256, 0, stream>>>(h2, batch, N, bn2_sum, bn2_sq, g2, be2, lw, lb, (float*)d_out);
}